// Round 13
// baseline (642.532 us; speedup 1.0000x reference)
//
#include <hip/hip_runtime.h>
#include <hip/hip_fp16.h>
#include <float.h>

typedef _Float16 half8 __attribute__((ext_vector_type(8)));
typedef _Float16 half4 __attribute__((ext_vector_type(4)));
typedef float floatx4 __attribute__((ext_vector_type(4)));

#define DD 256
#define D4 64            // DD/4
#define KK 8192
#define NROWS 32768
#define BM 64            // rows per tile (stage-1)
#define BM2 32           // list-rows per stage-2 tile
#define BM4 128          // rows per tile (round-4 fallback)
#define NELEM 8388608    // NROWS * DD
#define TAU1 2.5e-2f     // stage-1 margin
#define TAU2 2e-3f       // stage-2 margin
#define NSLICE 8
#define SLICE_K 1024
#define NBLOCKS13 1024   // 512-thr blocks, 4/CU co-resident -> 32 waves/CU
#define TPB13 4          // tiles per block (v13)
#define NBLOCKS2 1024    // fallback stage-1 grid
#define TILES_PER_BLOCK 4

// ---- ws layout (bytes) ----
// 0        znorm    (32768 f)          -> 131072
// 131072   cbnorm   (8192 f)           -> 163840
// 163840   codes    (32768 i32)        -> 294912
// 294912   loss partials (8192 f)      -> 327680
// 327680   cnt(i32) cnt2(i32)          -> 327696
// 327696   list     (32768 i32)        -> 458768
// 460800   list2    (32768 i32)        -> 591872
// 593920   pd       (1MB)              -> 1642496
// 1642496  ps       (1MB)              -> 2691072
// 2691072  pk       (1MB i32)          -> 3739648
// 4194304  bhi      (4MB)              -> 8388608
// 8388608  blo      (4MB)              -> 12582912
// 12582912 zg       (16MB, pre-swizzled fp16 z tiles) -> 29360128
#define WS_V9_BYTES      29360128
#define WS_CASCADE_BYTES 12582912
#define WS_R4_REFINE_BYTES 458768
#define WS_R4_FULL_BYTES   8849408

__global__ __launch_bounds__(256) void norms_kernel(
    const float* __restrict__ z, const float* __restrict__ cb,
    float* __restrict__ znorm, float* __restrict__ cbnorm)
{
    int wave = threadIdx.x >> 6;
    int lane = threadIdx.x & 63;
    int row = blockIdx.x * 4 + wave;
    const float4* src;
    float* dst;
    int r;
    if (row < NROWS) { src = (const float4*)z;  dst = znorm;  r = row; }
    else             { src = (const float4*)cb; dst = cbnorm; r = row - NROWS; }
    float4 v = src[(size_t)r * D4 + lane];
    float s = v.x*v.x + v.y*v.y + v.z*v.z + v.w*v.w;
    #pragma unroll
    for (int off = 1; off < 64; off <<= 1) s += __shfl_xor(s, off);
    if (lane == 0) dst[r] = s;
}

// fp16 hi/lo planes of 16*cb
__global__ __launch_bounds__(256) void preconv_kernel(
    const float* __restrict__ cb, _Float16* __restrict__ bhi, _Float16* __restrict__ blo)
{
    size_t e4 = (size_t)blockIdx.x * 256 + threadIdx.x;
    float4 v = ((const float4*)cb)[e4];
    float t0 = v.x * 16.f, t1 = v.y * 16.f, t2 = v.z * 16.f, t3 = v.w * 16.f;
    _Float16 h0 = (_Float16)t0, h1 = (_Float16)t1, h2 = (_Float16)t2, h3 = (_Float16)t3;
    _Float16 l0 = (_Float16)((t0 - (float)h0) * 2048.f);
    _Float16 l1 = (_Float16)((t1 - (float)h1) * 2048.f);
    _Float16 l2 = (_Float16)((t2 - (float)h2) * 2048.f);
    _Float16 l3 = (_Float16)((t3 - (float)h3) * 2048.f);
    reinterpret_cast<half4*>(bhi)[e4] = half4{h0, h1, h2, h3};
    reinterpret_cast<half4*>(blo)[e4] = half4{l0, l1, l2, l3};
}

// z -> fp16, stored as the pre-swizzled 64-row tile LDS image:
// byte offset = tile*32768 + r*512 + (g^(r&7))*16, group g = 8 halfs (2 float4)
__global__ __launch_bounds__(256) void preconv_z_kernel(
    const float* __restrict__ z, _Float16* __restrict__ zg)
{
    int gid = blockIdx.x * 256 + threadIdx.x;    // 0..1048575
    int row = gid >> 5;
    int g   = gid & 31;
    int r   = row & 63;
    const float4* src = (const float4*)z + (size_t)row * D4 + g * 2;
    float4 a = src[0], b = src[1];
    half8 h = { (_Float16)a.x, (_Float16)a.y, (_Float16)a.z, (_Float16)a.w,
                (_Float16)b.x, (_Float16)b.y, (_Float16)b.z, (_Float16)b.w };
    int gp = g ^ (r & 7);
    *reinterpret_cast<half8*>((char*)zg + (size_t)(row >> 6) * 32768 + r * 512 + gp * 16) = h;
}

// ---------------- stage 1 v13: v12 K-loop body, 512 threads (8 waves) per 32KB tile ----------------
// 8 cg groups x 32 codes = 256 codes/kt, 4 kt per slice. 4 blocks/CU -> 32 waves/CU.
__global__ __launch_bounds__(512, 4) void vq_fp16_v13(
    const _Float16* __restrict__ zg,
    const _Float16* __restrict__ bhip, const float* __restrict__ cbnorm,
    float* __restrict__ pd, float* __restrict__ ps, int* __restrict__ pk)
{
    __shared__ _Float16 zt[BM * DD];   // 32 KB (pre-swizzled image)

    const int tid  = threadIdx.x;
    const int lane = tid & 63;
    const int cg   = tid >> 6;          // wave = col group 0..7
    const int l15  = lane & 15;
    const int lhi  = lane >> 4;
    const int slice = blockIdx.x & 7;
    const int grp   = blockIdx.x >> 3;  // 0..127

    // A addressing: byteOff(rf,dc) = Ar[rf] ^ (dc<<6)  [on-device validated r9-r12]
    const int A0 = l15 * 512 + ((lhi ^ (l15 & 3)) << 4) + (((l15 >> 2) & 1) << 6);
    int Ar[4];
    #pragma unroll
    for (int rf = 0; rf < 4; ++rf) Ar[rf] = A0 + rf * 8192;
    const char* zbase = (const char*)zt;

    // B base: fragment (cf,dc) of step kt at bp[kt*8192 + cf*512 + dc*4]
    const half8* bp = (const half8*)bhip + ((size_t)(slice * SLICE_K + cg * 32 + l15) * 32 + lhi);
    const float* cnp = cbnorm + slice * SLICE_K + cg * 32 + l15;
    const int kbase = slice * SLICE_K + cg * 32 + l15;

    #pragma unroll 1
    for (int j = 0; j < TPB13; ++j) {
        const int tileIdx = grp * TPB13 + j;    // 0..511
        const int rowBase = tileIdx * BM;

        __syncthreads();   // previous iter's LDS use done
        // stage: pure 32KB copy of the pre-swizzled tile (2048 float4 / 512 thr)
        {
            const float4* src = (const float4*)((const char*)zg + (size_t)tileIdx * 32768);
            float4* dst = (float4*)zt;
            #pragma unroll
            for (int i = 0; i < 4; ++i) dst[i * 512 + tid] = src[i * 512 + tid];
        }

        float bestd[4][4], secd[4][4];
        int   bestk[4][4];
        #pragma unroll
        for (int rf = 0; rf < 4; ++rf)
            #pragma unroll
            for (int reg = 0; reg < 4; ++reg) {
                bestd[rf][reg] = FLT_MAX; secd[rf][reg] = FLT_MAX; bestk[rf][reg] = 0;
            }

        __syncthreads();

        #pragma unroll 1
        for (int kt = 0; kt < SLICE_K / 256; ++kt) {   // 4 steps of 256 codes
            floatx4 acc[4][2];
            #pragma unroll
            for (int rf = 0; rf < 4; ++rf)
                #pragma unroll
                for (int cf = 0; cf < 2; ++cf)
                    acc[rf][cf] = floatx4{0.f, 0.f, 0.f, 0.f};

            const half8* b0 = bp + kt * 8192;    // cf=0 fragments
            const half8* b1 = b0 + 512;          // cf=1 fragments

            #pragma unroll 2
            for (int dc = 0; dc < 8; ++dc) {     // unroll 2: bounds live B regs (r9/r10 spill lesson)
                half8 f0 = b0[dc * 4];
                half8 f1 = b1[dc * 4];
                #pragma unroll
                for (int rf = 0; rf < 4; ++rf) {
                    half8 a = *reinterpret_cast<const half8*>(zbase + (Ar[rf] ^ (dc << 6)));
                    acc[rf][0] = __builtin_amdgcn_mfma_f32_16x16x32_f16(a, f0, acc[rf][0], 0, 0, 0);
                    acc[rf][1] = __builtin_amdgcn_mfma_f32_16x16x32_f16(a, f1, acc[rf][1], 0, 0, 0);
                }
            }

            // m = cn - 0.125*dot16 (argmin-equivalent); track top-2
            const float cn0 = cnp[kt * 256];
            const float cn1 = cnp[kt * 256 + 16];
            const int k0 = kbase + kt * 256;
            #pragma unroll
            for (int cf = 0; cf < 2; ++cf) {
                const float cn = cf ? cn1 : cn0;
                const int k = k0 + cf * 16;
                #pragma unroll
                for (int rf = 0; rf < 4; ++rf)
                    #pragma unroll
                    for (int reg = 0; reg < 4; ++reg) {
                        float m = fmaf(-0.125f, acc[rf][cf][reg], cn);
                        float w = fmaxf(bestd[rf][reg], m);
                        secd[rf][reg] = fminf(secd[rf][reg], w);
                        if (m < bestd[rf][reg]) { bestd[rf][reg] = m; bestk[rf][reg] = k; }
                    }
            }
        }

        // reduce across 16 code-lanes, lexicographic (m,k), carrying second-best
        #pragma unroll
        for (int off = 1; off < 16; off <<= 1) {
            #pragma unroll
            for (int rf = 0; rf < 4; ++rf)
                #pragma unroll
                for (int reg = 0; reg < 4; ++reg) {
                    float od = __shfl_xor(bestd[rf][reg], off);
                    int   ok = __shfl_xor(bestk[rf][reg], off);
                    float os = __shfl_xor(secd[rf][reg], off);
                    float hi = fmaxf(bestd[rf][reg], od);
                    secd[rf][reg] = fminf(fminf(secd[rf][reg], os), hi);
                    if (od < bestd[rf][reg] || (od == bestd[rf][reg] && ok < bestk[rf][reg])) {
                        bestd[rf][reg] = od; bestk[rf][reg] = ok;
                    }
                }
        }

        // cross-cg reduce (8 groups) via LDS scratch (reuse zt), write per-slice partials
        __syncthreads();
        float* dsc = reinterpret_cast<float*>(zt);          // [8][64]
        int*   ksc = reinterpret_cast<int*>(zt) + 512;      // [8][64]
        float* ssc = reinterpret_cast<float*>(zt) + 1024;   // [8][64]
        if (l15 == 0) {
            #pragma unroll
            for (int rf = 0; rf < 4; ++rf)
                #pragma unroll
                for (int reg = 0; reg < 4; ++reg) {
                    int rrow = rf * 16 + lhi * 4 + reg;
                    dsc[cg * 64 + rrow] = bestd[rf][reg];
                    ksc[cg * 64 + rrow] = bestk[rf][reg];
                    ssc[cg * 64 + rrow] = secd[rf][reg];
                }
        }
        __syncthreads();
        if (tid < 64) {
            float bd = dsc[tid];
            int   bk = ksc[tid];
            float sd = ssc[tid];
            #pragma unroll
            for (int c = 1; c < 8; ++c) {
                float od = dsc[c * 64 + tid];
                int   ok = ksc[c * 64 + tid];
                float os = ssc[c * 64 + tid];
                float hi = fmaxf(bd, od);
                sd = fminf(fminf(sd, os), hi);
                if (od < bd || (od == bd && ok < bk)) { bd = od; bk = ok; }
            }
            int row = rowBase + tid;
            pd[row * NSLICE + slice] = bd;
            ps[row * NSLICE + slice] = sd;
            pk[row * NSLICE + slice] = bk;
        }
    }
}

// ---------------- r8 stage-1 fallback (reads raw z) ----------------
__global__ __launch_bounds__(256, 4) void vq_fp16_kernel(
    const float* __restrict__ z,
    const _Float16* __restrict__ bhip, const float* __restrict__ cbnorm,
    float* __restrict__ pd, float* __restrict__ ps, int* __restrict__ pk)
{
    __shared__ _Float16 zhi[BM * DD];
    const int tid  = threadIdx.x;
    const int lane = tid & 63;
    const int cg   = tid >> 6;
    const int l15  = lane & 15;
    const int lhi  = lane >> 4;
    const int slice = blockIdx.x & 7;
    const int grp   = blockIdx.x >> 3;
    const int sliceBase = slice * SLICE_K;

    int rowA[4];
    #pragma unroll
    for (int rf = 0; rf < 4; ++rf) rowA[rf] = rf * 16 + l15;

    #pragma unroll 1
    for (int j = 0; j < TILES_PER_BLOCK; ++j) {
        const int rowBase = (grp * TILES_PER_BLOCK + j) * BM;
        __syncthreads();
        #pragma unroll
        for (int i = 0; i < 16; ++i) {
            int gid = i * 256 + tid;
            int r   = gid >> 6;
            int c4  = gid & 63;
            float4 v = ((const float4*)z)[(size_t)(rowBase + r) * D4 + c4];
            _Float16 h0 = (_Float16)v.x, h1 = (_Float16)v.y,
                     h2 = (_Float16)v.z, h3 = (_Float16)v.w;
            int g = c4 >> 1;
            int byteOff = r * 512 + ((g ^ (r & 7)) << 4) + ((c4 & 1) << 3);
            *reinterpret_cast<half4*>(reinterpret_cast<char*>(zhi) + byteOff) = half4{h0, h1, h2, h3};
        }
        float bestd[4][4], secd[4][4];
        int   bestk[4][4];
        #pragma unroll
        for (int rf = 0; rf < 4; ++rf)
            #pragma unroll
            for (int reg = 0; reg < 4; ++reg) {
                bestd[rf][reg] = FLT_MAX; secd[rf][reg] = FLT_MAX; bestk[rf][reg] = 0;
            }
        __syncthreads();
        #pragma unroll 1
        for (int kt = 0; kt < SLICE_K / 128; ++kt) {
            floatx4 acc[4][2];
            #pragma unroll
            for (int rf = 0; rf < 4; ++rf)
                #pragma unroll
                for (int cf = 0; cf < 2; ++cf)
                    acc[rf][cf] = floatx4{0.f, 0.f, 0.f, 0.f};
            const int codeBase = sliceBase + kt * 128 + cg * 32 + l15;
            #pragma unroll 2
            for (int dc = 0; dc < 8; ++dc) {
                half8 bhi_f[2];
                #pragma unroll
                for (int cf = 0; cf < 2; ++cf) {
                    size_t off = (size_t)(codeBase + 16 * cf) * DD + dc * 32 + lhi * 8;
                    bhi_f[cf] = *reinterpret_cast<const half8*>(bhip + off);
                }
                #pragma unroll
                for (int rf = 0; rf < 4; ++rf) {
                    int g = dc * 4 + lhi;
                    int off = rowA[rf] * 512 + ((g ^ (rowA[rf] & 7)) << 4);
                    half8 ahi = *reinterpret_cast<const half8*>(reinterpret_cast<const char*>(zhi) + off);
                    #pragma unroll
                    for (int cf = 0; cf < 2; ++cf)
                        acc[rf][cf] = __builtin_amdgcn_mfma_f32_16x16x32_f16(ahi, bhi_f[cf], acc[rf][cf], 0, 0, 0);
                }
            }
            #pragma unroll
            for (int cf = 0; cf < 2; ++cf) {
                int k = codeBase + 16 * cf;
                float cn = cbnorm[k];
                #pragma unroll
                for (int rf = 0; rf < 4; ++rf)
                    #pragma unroll
                    for (int reg = 0; reg < 4; ++reg) {
                        float m = fmaf(-0.125f, acc[rf][cf][reg], cn);
                        float w = fmaxf(bestd[rf][reg], m);
                        secd[rf][reg] = fminf(secd[rf][reg], w);
                        if (m < bestd[rf][reg]) { bestd[rf][reg] = m; bestk[rf][reg] = k; }
                    }
            }
        }
        #pragma unroll
        for (int off = 1; off < 16; off <<= 1) {
            #pragma unroll
            for (int rf = 0; rf < 4; ++rf)
                #pragma unroll
                for (int reg = 0; reg < 4; ++reg) {
                    float od = __shfl_xor(bestd[rf][reg], off);
                    int   ok = __shfl_xor(bestk[rf][reg], off);
                    float os = __shfl_xor(secd[rf][reg], off);
                    float hi = fmaxf(bestd[rf][reg], od);
                    secd[rf][reg] = fminf(fminf(secd[rf][reg], os), hi);
                    if (od < bestd[rf][reg] || (od == bestd[rf][reg] && ok < bestk[rf][reg])) {
                        bestd[rf][reg] = od; bestk[rf][reg] = ok;
                    }
                }
        }
        __syncthreads();
        float* dsc = reinterpret_cast<float*>(zhi);
        int*   ksc = reinterpret_cast<int*>(zhi) + 256;
        float* ssc = reinterpret_cast<float*>(zhi) + 512;
        if (l15 == 0) {
            #pragma unroll
            for (int rf = 0; rf < 4; ++rf)
                #pragma unroll
                for (int reg = 0; reg < 4; ++reg) {
                    int rrow = rf * 16 + lhi * 4 + reg;
                    dsc[cg * 64 + rrow] = bestd[rf][reg];
                    ksc[cg * 64 + rrow] = bestk[rf][reg];
                    ssc[cg * 64 + rrow] = secd[rf][reg];
                }
        }
        __syncthreads();
        if (tid < 64) {
            float bd = dsc[tid];
            int   bk = ksc[tid];
            float sd = ssc[tid];
            #pragma unroll
            for (int c = 1; c < 4; ++c) {
                float od = dsc[c * 64 + tid];
                int   ok = ksc[c * 64 + tid];
                float os = ssc[c * 64 + tid];
                float hi = fmaxf(bd, od);
                sd = fminf(fminf(sd, os), hi);
                if (od < bd || (od == bd && ok < bk)) { bd = od; bk = ok; }
            }
            int row = rowBase + tid;
            pd[row * NSLICE + slice] = bd;
            ps[row * NSLICE + slice] = sd;
            pk[row * NSLICE + slice] = bk;
        }
    }
}

__global__ __launch_bounds__(256) void slice_reduce_kernel(
    const float* __restrict__ pd, const float* __restrict__ ps, const int* __restrict__ pk,
    int* __restrict__ codes, float* __restrict__ codes_f,
    int* __restrict__ cnt, int* __restrict__ list, float tau)
{
    int row = blockIdx.x * 256 + threadIdx.x;
    float bd = FLT_MAX, sd = FLT_MAX;
    int bk = 0;
    #pragma unroll
    for (int s = 0; s < NSLICE; ++s) {
        float d  = pd[row * NSLICE + s];
        int   k  = pk[row * NSLICE + s];
        float s2 = ps[row * NSLICE + s];
        float hi = fmaxf(bd, d);
        sd = fminf(fminf(sd, s2), hi);
        if (d < bd || (d == bd && k < bk)) { bd = d; bk = k; }
    }
    codes[row]   = bk;
    codes_f[row] = (float)bk;
    if ((sd - bd) < tau) {
        int idx = atomicAdd(cnt, 1);
        list[idx] = row;
    }
}

// stage 2: hi/lo MFMA rescan of flagged rows (r8, proven)
__global__ __launch_bounds__(256, 4) void vq_refine2_kernel(
    const float* __restrict__ z,
    const _Float16* __restrict__ bhip, const _Float16* __restrict__ blop,
    const float* __restrict__ cbnorm,
    const int* __restrict__ cnt, const int* __restrict__ list,
    float* __restrict__ pd, float* __restrict__ ps, int* __restrict__ pk)
{
    __shared__ _Float16 zhi[BM2 * DD];
    __shared__ _Float16 zlo[BM2 * DD];

    const int n1 = *cnt;
    if (n1 == 0) return;
    const int ntiles = (n1 + BM2 - 1) / BM2;
    const int njobs = ntiles * NSLICE;

    const int tid  = threadIdx.x;
    const int lane = tid & 63;
    const int cg   = tid >> 6;
    const int l15  = lane & 15;
    const int lhi  = lane >> 4;

    int rowA[2];
    #pragma unroll
    for (int rf = 0; rf < 2; ++rf) rowA[rf] = rf * 16 + l15;

    for (int job = blockIdx.x; job < njobs; job += gridDim.x) {
        const int slice = job & 7;
        const int tile  = job >> 3;
        const int base  = tile * BM2;
        const int sliceBase = slice * SLICE_K;

        __syncthreads();
        #pragma unroll
        for (int i = 0; i < 8; ++i) {
            int gid = i * 256 + tid;
            int r   = gid >> 6;
            int c4  = gid & 63;
            int pos = base + r;
            int row = list[pos < n1 ? pos : (n1 - 1)];
            float4 v = ((const float4*)z)[(size_t)row * D4 + c4];
            _Float16 h0 = (_Float16)v.x, h1 = (_Float16)v.y,
                     h2 = (_Float16)v.z, h3 = (_Float16)v.w;
            _Float16 e0 = (_Float16)((v.x - (float)h0) * 2048.f);
            _Float16 e1 = (_Float16)((v.y - (float)h1) * 2048.f);
            _Float16 e2 = (_Float16)((v.z - (float)h2) * 2048.f);
            _Float16 e3 = (_Float16)((v.w - (float)h3) * 2048.f);
            int g = c4 >> 1;
            int byteOff = r * 512 + ((g ^ (r & 7)) << 4) + ((c4 & 1) << 3);
            *reinterpret_cast<half4*>(reinterpret_cast<char*>(zhi) + byteOff) = half4{h0, h1, h2, h3};
            *reinterpret_cast<half4*>(reinterpret_cast<char*>(zlo) + byteOff) = half4{e0, e1, e2, e3};
        }

        float bestd[2][4], secd[2][4];
        int   bestk[2][4];
        #pragma unroll
        for (int rf = 0; rf < 2; ++rf)
            #pragma unroll
            for (int reg = 0; reg < 4; ++reg) {
                bestd[rf][reg] = FLT_MAX; secd[rf][reg] = FLT_MAX; bestk[rf][reg] = 0;
            }

        __syncthreads();

        #pragma unroll 1
        for (int kt = 0; kt < SLICE_K / 128; ++kt) {
            floatx4 accH[2][2], accM[2][2];
            #pragma unroll
            for (int rf = 0; rf < 2; ++rf)
                #pragma unroll
                for (int cf = 0; cf < 2; ++cf) {
                    accH[rf][cf] = floatx4{0.f, 0.f, 0.f, 0.f};
                    accM[rf][cf] = floatx4{0.f, 0.f, 0.f, 0.f};
                }
            const int codeBase = sliceBase + kt * 128 + cg * 32 + l15;
            #pragma unroll 2
            for (int dc = 0; dc < 8; ++dc) {
                half8 bhi_f[2], blo_f[2];
                #pragma unroll
                for (int cf = 0; cf < 2; ++cf) {
                    size_t off = (size_t)(codeBase + 16 * cf) * DD + dc * 32 + lhi * 8;
                    bhi_f[cf] = *reinterpret_cast<const half8*>(bhip + off);
                    blo_f[cf] = *reinterpret_cast<const half8*>(blop + off);
                }
                #pragma unroll
                for (int rf = 0; rf < 2; ++rf) {
                    int g = dc * 4 + lhi;
                    int off = rowA[rf] * 512 + ((g ^ (rowA[rf] & 7)) << 4);
                    half8 ahi = *reinterpret_cast<const half8*>(reinterpret_cast<const char*>(zhi) + off);
                    half8 alo = *reinterpret_cast<const half8*>(reinterpret_cast<const char*>(zlo) + off);
                    #pragma unroll
                    for (int cf = 0; cf < 2; ++cf) {
                        accH[rf][cf] = __builtin_amdgcn_mfma_f32_16x16x32_f16(ahi, bhi_f[cf], accH[rf][cf], 0, 0, 0);
                        accM[rf][cf] = __builtin_amdgcn_mfma_f32_16x16x32_f16(alo, bhi_f[cf], accM[rf][cf], 0, 0, 0);
                        accM[rf][cf] = __builtin_amdgcn_mfma_f32_16x16x32_f16(ahi, blo_f[cf], accM[rf][cf], 0, 0, 0);
                    }
                }
            }
            #pragma unroll
            for (int cf = 0; cf < 2; ++cf) {
                int k = codeBase + 16 * cf;
                float cn = cbnorm[k];
                #pragma unroll
                for (int rf = 0; rf < 2; ++rf)
                    #pragma unroll
                    for (int reg = 0; reg < 4; ++reg) {
                        float dot16 = fmaf(accM[rf][cf][reg], 0x1p-11f, accH[rf][cf][reg]);
                        float m = fmaf(-0.125f, dot16, cn);
                        float w = fmaxf(bestd[rf][reg], m);
                        secd[rf][reg] = fminf(secd[rf][reg], w);
                        if (m < bestd[rf][reg]) { bestd[rf][reg] = m; bestk[rf][reg] = k; }
                    }
            }
        }

        #pragma unroll
        for (int off = 1; off < 16; off <<= 1) {
            #pragma unroll
            for (int rf = 0; rf < 2; ++rf)
                #pragma unroll
                for (int reg = 0; reg < 4; ++reg) {
                    float od = __shfl_xor(bestd[rf][reg], off);
                    int   ok = __shfl_xor(bestk[rf][reg], off);
                    float os = __shfl_xor(secd[rf][reg], off);
                    float hi = fmaxf(bestd[rf][reg], od);
                    secd[rf][reg] = fminf(fminf(secd[rf][reg], os), hi);
                    if (od < bestd[rf][reg] || (od == bestd[rf][reg] && ok < bestk[rf][reg])) {
                        bestd[rf][reg] = od; bestk[rf][reg] = ok;
                    }
                }
        }

        __syncthreads();
        float* dsc = reinterpret_cast<float*>(zhi);
        int*   ksc = reinterpret_cast<int*>(zhi) + 128;
        float* ssc = reinterpret_cast<float*>(zhi) + 256;
        if (l15 == 0) {
            #pragma unroll
            for (int rf = 0; rf < 2; ++rf)
                #pragma unroll
                for (int reg = 0; reg < 4; ++reg) {
                    int rrow = rf * 16 + lhi * 4 + reg;
                    dsc[cg * 32 + rrow] = bestd[rf][reg];
                    ksc[cg * 32 + rrow] = bestk[rf][reg];
                    ssc[cg * 32 + rrow] = secd[rf][reg];
                }
        }
        __syncthreads();
        if (tid < 32) {
            float bd = dsc[tid];
            int   bk = ksc[tid];
            float sd = ssc[tid];
            #pragma unroll
            for (int c = 1; c < 4; ++c) {
                float od = dsc[c * 32 + tid];
                int   ok = ksc[c * 32 + tid];
                float os = ssc[c * 32 + tid];
                float hi = fmaxf(bd, od);
                sd = fminf(fminf(sd, os), hi);
                if (od < bd || (od == bd && ok < bk)) { bd = od; bk = ok; }
            }
            int pos = base + tid;
            pd[pos * NSLICE + slice] = bd;
            ps[pos * NSLICE + slice] = sd;
            pk[pos * NSLICE + slice] = bk;
        }
    }
}

__global__ __launch_bounds__(256) void slice_reduce2_kernel(
    const float* __restrict__ pd, const float* __restrict__ ps, const int* __restrict__ pk,
    const int* __restrict__ cnt, const int* __restrict__ list,
    int* __restrict__ codes, float* __restrict__ codes_f,
    int* __restrict__ cnt2, int* __restrict__ list2)
{
    const int n1 = *cnt;
    for (int i = blockIdx.x * 256 + threadIdx.x; i < n1; i += gridDim.x * 256) {
        float bd = FLT_MAX, sd = FLT_MAX;
        int bk = 0;
        #pragma unroll
        for (int s = 0; s < NSLICE; ++s) {
            float d  = pd[i * NSLICE + s];
            int   k  = pk[i * NSLICE + s];
            float s2 = ps[i * NSLICE + s];
            float hi = fmaxf(bd, d);
            sd = fminf(fminf(sd, s2), hi);
            if (d < bd || (d == bd && k < bk)) { bd = d; bk = k; }
        }
        int row = list[i];
        codes[row]   = bk;
        codes_f[row] = (float)bk;
        if ((sd - bd) < TAU2) {
            int idx = atomicAdd(cnt2, 1);
            list2[idx] = row;
        }
    }
}

// stage 3 / fallback: per-row exact fp32 re-argmin (round-1 numerics)
__global__ __launch_bounds__(256) void refine_kernel(
    const float* __restrict__ z, const float* __restrict__ cb,
    const float* __restrict__ znorm, const float* __restrict__ cbnorm,
    const int* __restrict__ cnt, const int* __restrict__ list,
    int* __restrict__ codes, float* __restrict__ codes_f)
{
    __shared__ float zrow[DD];
    __shared__ float dred[4];
    __shared__ int   kred[4];
    const int tid = threadIdx.x;
    const int lane = tid & 63;
    const int wv = tid >> 6;
    const int n = *cnt;
    for (int i = blockIdx.x; i < n; i += gridDim.x) {
        const int row = list[i];
        if (tid < 64) ((float4*)zrow)[tid] = ((const float4*)z)[(size_t)row * D4 + tid];
        const float zn = znorm[row];
        __syncthreads();
        float bd = FLT_MAX;
        int   bk = 0;
        for (int k = tid; k < KK; k += 256) {
            const float4* crow = (const float4*)cb + (size_t)k * D4;
            float acc = 0.f;
            #pragma unroll 8
            for (int d4 = 0; d4 < D4; ++d4) {
                float4 c = crow[d4];
                float4 zv = ((const float4*)zrow)[d4];
                acc = fmaf(zv.x, c.x, acc);
                acc = fmaf(zv.y, c.y, acc);
                acc = fmaf(zv.z, c.z, acc);
                acc = fmaf(zv.w, c.w, acc);
            }
            float dist = fmaf(-2.f, acc, zn) + cbnorm[k];
            if (dist < bd) { bd = dist; bk = k; }
        }
        #pragma unroll
        for (int off = 1; off < 64; off <<= 1) {
            float od = __shfl_xor(bd, off);
            int   ok = __shfl_xor(bk, off);
            if (od < bd || (od == bd && ok < bk)) { bd = od; bk = ok; }
        }
        if (lane == 0) { dred[wv] = bd; kred[wv] = bk; }
        __syncthreads();
        if (tid == 0) {
            #pragma unroll
            for (int c = 1; c < 4; ++c) {
                if (dred[c] < bd || (dred[c] == bd && kred[c] < bk)) { bd = dred[c]; bk = kred[c]; }
            }
            codes[row]   = bk;
            codes_f[row] = (float)bk;
        }
        __syncthreads();
    }
}

__global__ __launch_bounds__(256) void gather_loss_kernel(
    const float* __restrict__ z, const float* __restrict__ cb,
    const int* __restrict__ codes, float* __restrict__ zq_out,
    float* __restrict__ partials)
{
    __shared__ float red[4];
    int tid = threadIdx.x;
    size_t e4 = (size_t)blockIdx.x * 256 + tid;
    int row = (int)(e4 >> 6);
    int d4  = (int)(e4 & 63);
    int code = codes[row];
    float4 q  = ((const float4*)cb)[(size_t)code * D4 + d4];
    float4 zv = ((const float4*)z)[e4];
    float dx = q.x - zv.x, dy = q.y - zv.y, dz = q.z - zv.z, dw = q.w - zv.w;
    float4 o;
    o.x = zv.x + dx; o.y = zv.y + dy; o.z = zv.z + dz; o.w = zv.w + dw;
    ((float4*)zq_out)[e4] = o;
    float s = dx*dx + dy*dy + dz*dz + dw*dw;
    #pragma unroll
    for (int off = 1; off < 64; off <<= 1) s += __shfl_xor(s, off);
    if ((tid & 63) == 0) red[tid >> 6] = s;
    __syncthreads();
    if (tid == 0) partials[blockIdx.x] = ((red[0] + red[1]) + red[2]) + red[3];
}

__global__ __launch_bounds__(256) void final_loss_kernel(
    const float* __restrict__ partials, float* __restrict__ out_loss)
{
    __shared__ float red[4];
    int tid = threadIdx.x;
    float s = 0.f;
    #pragma unroll 4
    for (int i = 0; i < 32; ++i) s += partials[tid * 32 + i];
    #pragma unroll
    for (int off = 1; off < 64; off <<= 1) s += __shfl_xor(s, off);
    if ((tid & 63) == 0) red[tid >> 6] = s;
    __syncthreads();
    if (tid == 0) {
        float tot = ((red[0] + red[1]) + red[2]) + red[3];
        out_loss[0] = 0.5f * (tot / (float)NELEM);
    }
}

// ---------------- round-4 fallback kernel (proven, tiny-ws path) ----------------
template <bool PRECONV, bool REFINE>
__global__ __launch_bounds__(512, 1) void vq_mfma_kernel(
    const float* __restrict__ z, const float* __restrict__ cb,
    const _Float16* __restrict__ bhip, const _Float16* __restrict__ blop,
    const float* __restrict__ znorm, const float* __restrict__ cbnorm,
    int* __restrict__ codes, float* __restrict__ codes_f,
    int* __restrict__ cnt, int* __restrict__ list)
{
    __shared__ _Float16 zhi[BM4 * DD];
    __shared__ _Float16 zlo[BM4 * DD];
    const int tid  = threadIdx.x;
    const int lane = tid & 63;
    const int w    = tid >> 6;
    const int rg   = w >> 2;
    const int cg   = w & 3;
    const int l15  = lane & 15;
    const int lhi  = lane >> 4;
    const int rowBase = blockIdx.x * BM4;

    #pragma unroll
    for (int i = 0; i < 16; ++i) {
        int gid = i * 512 + tid;
        int r   = gid >> 6;
        int c4  = gid & 63;
        float4 v = ((const float4*)z)[(size_t)(rowBase + r) * D4 + c4];
        _Float16 h0 = (_Float16)v.x, h1 = (_Float16)v.y,
                 h2 = (_Float16)v.z, h3 = (_Float16)v.w;
        _Float16 e0 = (_Float16)((v.x - (float)h0) * 2048.f);
        _Float16 e1 = (_Float16)((v.y - (float)h1) * 2048.f);
        _Float16 e2 = (_Float16)((v.z - (float)h2) * 2048.f);
        _Float16 e3 = (_Float16)((v.w - (float)h3) * 2048.f);
        int g = c4 >> 1;
        int byteOff = r * 512 + (((g ^ (r & 7))) << 4) + ((c4 & 1) << 3);
        *reinterpret_cast<half4*>(reinterpret_cast<char*>(zhi) + byteOff) = half4{h0, h1, h2, h3};
        *reinterpret_cast<half4*>(reinterpret_cast<char*>(zlo) + byteOff) = half4{e0, e1, e2, e3};
    }
    int rowA[4];
    #pragma unroll
    for (int rf = 0; rf < 4; ++rf) rowA[rf] = rg * 64 + rf * 16 + l15;
    float zn[4][4];
    #pragma unroll
    for (int rf = 0; rf < 4; ++rf)
        #pragma unroll
        for (int reg = 0; reg < 4; ++reg)
            zn[rf][reg] = znorm[rowBase + rg * 64 + rf * 16 + lhi * 4 + reg];
    float bestd[4][4], secd[4][4];
    int   bestk[4][4];
    #pragma unroll
    for (int rf = 0; rf < 4; ++rf)
        #pragma unroll
        for (int reg = 0; reg < 4; ++reg) {
            bestd[rf][reg] = FLT_MAX; secd[rf][reg] = FLT_MAX; bestk[rf][reg] = 0;
        }
    __syncthreads();
    for (int kt = 0; kt < KK / 256; ++kt) {
        floatx4 accH[4][4], accM[4][4];
        #pragma unroll
        for (int rf = 0; rf < 4; ++rf)
            #pragma unroll
            for (int cf = 0; cf < 4; ++cf) {
                accH[rf][cf] = floatx4{0.f, 0.f, 0.f, 0.f};
                accM[rf][cf] = floatx4{0.f, 0.f, 0.f, 0.f};
            }
        const int codeBase = kt * 256 + cg * 64 + l15;
        for (int dc = 0; dc < 8; ++dc) {
            half8 bhi_f[4], blo_f[4];
            #pragma unroll
            for (int cf = 0; cf < 4; ++cf) {
                if (PRECONV) {
                    size_t off = (size_t)(codeBase + 16 * cf) * DD + dc * 32 + lhi * 8;
                    bhi_f[cf] = *reinterpret_cast<const half8*>(bhip + off);
                    blo_f[cf] = *reinterpret_cast<const half8*>(blop + off);
                } else {
                    const float4* p = (const float4*)(cb + (size_t)(codeBase + 16 * cf) * DD + dc * 32 + lhi * 8);
                    float4 u0 = p[0];
                    float4 u1 = p[1];
                    float uv[8] = {u0.x, u0.y, u0.z, u0.w, u1.x, u1.y, u1.z, u1.w};
                    half8 bh, bl;
                    #pragma unroll
                    for (int jj = 0; jj < 8; ++jj) {
                        float t = uv[jj] * 16.f;
                        _Float16 h = (_Float16)t;
                        bh[jj] = h;
                        bl[jj] = (_Float16)((t - (float)h) * 2048.f);
                    }
                    bhi_f[cf] = bh; blo_f[cf] = bl;
                }
            }
            #pragma unroll
            for (int rf = 0; rf < 4; ++rf) {
                int g = dc * 4 + lhi;
                int off = rowA[rf] * 512 + ((g ^ (rowA[rf] & 7)) << 4);
                half8 ahi = *reinterpret_cast<const half8*>(reinterpret_cast<const char*>(zhi) + off);
                half8 alo = *reinterpret_cast<const half8*>(reinterpret_cast<const char*>(zlo) + off);
                #pragma unroll
                for (int cf = 0; cf < 4; ++cf) {
                    accH[rf][cf] = __builtin_amdgcn_mfma_f32_16x16x32_f16(ahi, bhi_f[cf], accH[rf][cf], 0, 0, 0);
                    accM[rf][cf] = __builtin_amdgcn_mfma_f32_16x16x32_f16(alo, bhi_f[cf], accM[rf][cf], 0, 0, 0);
                    accM[rf][cf] = __builtin_amdgcn_mfma_f32_16x16x32_f16(ahi, blo_f[cf], accM[rf][cf], 0, 0, 0);
                }
            }
        }
        #pragma unroll
        for (int cf = 0; cf < 4; ++cf) {
            int k = codeBase + 16 * cf;
            float cn = cbnorm[k];
            #pragma unroll
            for (int rf = 0; rf < 4; ++rf)
                #pragma unroll
                for (int reg = 0; reg < 4; ++reg) {
                    float dot16 = fmaf(accM[rf][cf][reg], 0x1p-11f, accH[rf][cf][reg]);
                    float dist  = fmaf(-0.125f, dot16, zn[rf][reg]) + cn;
                    float wv2 = fmaxf(bestd[rf][reg], dist);
                    secd[rf][reg] = fminf(secd[rf][reg], wv2);
                    if (dist < bestd[rf][reg]) { bestd[rf][reg] = dist; bestk[rf][reg] = k; }
                }
        }
    }
    #pragma unroll
    for (int off = 1; off < 16; off <<= 1) {
        #pragma unroll
        for (int rf = 0; rf < 4; ++rf)
            #pragma unroll
            for (int reg = 0; reg < 4; ++reg) {
                float od = __shfl_xor(bestd[rf][reg], off);
                int   ok = __shfl_xor(bestk[rf][reg], off);
                float os = __shfl_xor(secd[rf][reg], off);
                float hi = fmaxf(bestd[rf][reg], od);
                secd[rf][reg] = fminf(fminf(secd[rf][reg], os), hi);
                if (od < bestd[rf][reg] || (od == bestd[rf][reg] && ok < bestk[rf][reg])) {
                    bestd[rf][reg] = od; bestk[rf][reg] = ok;
                }
            }
    }
    __syncthreads();
    float* dsc = reinterpret_cast<float*>(zhi);
    int*   ksc = reinterpret_cast<int*>(zhi) + 512;
    float* ssc = reinterpret_cast<float*>(zhi) + 1024;
    if (l15 == 0) {
        #pragma unroll
        for (int rf = 0; rf < 4; ++rf)
            #pragma unroll
            for (int reg = 0; reg < 4; ++reg) {
                int rrow = rg * 64 + rf * 16 + lhi * 4 + reg;
                dsc[cg * 128 + rrow] = bestd[rf][reg];
                ksc[cg * 128 + rrow] = bestk[rf][reg];
                ssc[cg * 128 + rrow] = secd[rf][reg];
            }
    }
    __syncthreads();
    if (tid < 128) {
        float bd = dsc[tid];
        int   bk = ksc[tid];
        float sd = ssc[tid];
        #pragma unroll
        for (int c = 1; c < 4; ++c) {
            float od = dsc[c * 128 + tid];
            int   ok = ksc[c * 128 + tid];
            float os = ssc[c * 128 + tid];
            float hi = fmaxf(bd, od);
            sd = fminf(fminf(sd, os), hi);
            if (od < bd || (od == bd && ok < bk)) { bd = od; bk = ok; }
        }
        int row = rowBase + tid;
        codes[row]   = bk;
        codes_f[row] = (float)bk;
        if (REFINE && (sd - bd) < TAU2) {
            int idx = atomicAdd(cnt, 1);
            list[idx] = row;
        }
    }
}

extern "C" void kernel_launch(void* const* d_in, const int* in_sizes, int n_in,
                              void* d_out, int out_size, void* d_ws, size_t ws_size,
                              hipStream_t stream) {
    const float* z  = (const float*)d_in[0];
    const float* cb = (const float*)d_in[1];
    float* out      = (float*)d_out;
    float* zq_out   = out;
    float* loss_out = out + NELEM;
    float* codes_f  = out + NELEM + 1;

    char* wsb       = (char*)d_ws;
    float* znorm    = (float*)(wsb + 0);
    float* cbnorm   = (float*)(wsb + 131072);
    int*   codes    = (int*)(wsb + 163840);
    float* partials = (float*)(wsb + 294912);
    int*   cnt      = (int*)(wsb + 327680);
    int*   cnt2     = (int*)(wsb + 327684);
    int*   list     = (int*)(wsb + 327696);

    norms_kernel<<<10240, 256, 0, stream>>>(z, cb, znorm, cbnorm);

    if (ws_size >= (size_t)WS_CASCADE_BYTES) {
        int*   list2  = (int*)(wsb + 460800);
        float* pd     = (float*)(wsb + 593920);
        float* ps     = (float*)(wsb + 1642496);
        int*   pk     = (int*)(wsb + 2691072);
        _Float16* bhi = (_Float16*)(wsb + 4194304);
        _Float16* blo = (_Float16*)(wsb + 8388608);
        hipMemsetAsync(cnt, 0, 8, stream);
        preconv_kernel<<<2048, 256, 0, stream>>>(cb, bhi, blo);
        if (ws_size >= (size_t)WS_V9_BYTES) {
            _Float16* zg = (_Float16*)(wsb + 12582912);
            preconv_z_kernel<<<4096, 256, 0, stream>>>(z, zg);
            vq_fp16_v13<<<NBLOCKS13, 512, 0, stream>>>(zg, bhi, cbnorm, pd, ps, pk);
        } else {
            vq_fp16_kernel<<<NBLOCKS2, 256, 0, stream>>>(z, bhi, cbnorm, pd, ps, pk);
        }
        slice_reduce_kernel<<<128, 256, 0, stream>>>(pd, ps, pk, codes, codes_f, cnt, list, TAU1);
        vq_refine2_kernel<<<512, 256, 0, stream>>>(z, bhi, blo, cbnorm, cnt, list, pd, ps, pk);
        slice_reduce2_kernel<<<64, 256, 0, stream>>>(pd, ps, pk, cnt, list, codes, codes_f, cnt2, list2);
        refine_kernel<<<256, 256, 0, stream>>>(z, cb, znorm, cbnorm, cnt2, list2, codes, codes_f);
    } else {
        _Float16* bhi = (_Float16*)(wsb + 460800);
        _Float16* blo = (_Float16*)(wsb + 4655104);
        const bool preconv = ws_size >= (size_t)WS_R4_FULL_BYTES;
        const bool refine  = ws_size >= (size_t)WS_R4_REFINE_BYTES;
        if (refine) hipMemsetAsync(cnt, 0, sizeof(int), stream);
        if (preconv) preconv_kernel<<<2048, 256, 0, stream>>>(cb, bhi, blo);
        if (preconv && refine)
            vq_mfma_kernel<true, true><<<NROWS / BM4, 512, 0, stream>>>(z, cb, bhi, blo, znorm, cbnorm, codes, codes_f, cnt, list);
        else if (preconv)
            vq_mfma_kernel<true, false><<<NROWS / BM4, 512, 0, stream>>>(z, cb, bhi, blo, znorm, cbnorm, codes, codes_f, cnt, list);
        else if (refine)
            vq_mfma_kernel<false, true><<<NROWS / BM4, 512, 0, stream>>>(z, cb, bhi, blo, znorm, cbnorm, codes, codes_f, cnt, list);
        else
            vq_mfma_kernel<false, false><<<NROWS / BM4, 512, 0, stream>>>(z, cb, bhi, blo, znorm, cbnorm, codes, codes_f, cnt, list);
        if (refine)
            refine_kernel<<<256, 256, 0, stream>>>(z, cb, znorm, cbnorm, cnt, list, codes, codes_f);
    }

    gather_loss_kernel<<<8192, 256, 0, stream>>>(z, cb, codes, zq_out, partials);
    final_loss_kernel<<<1, 256, 0, stream>>>(partials, loss_out);
}

// Round 14
// 595.081 us; speedup vs baseline: 1.0797x; 1.0797x over previous
//
#include <hip/hip_runtime.h>
#include <hip/hip_fp16.h>
#include <float.h>

typedef _Float16 half8 __attribute__((ext_vector_type(8)));
typedef _Float16 half4 __attribute__((ext_vector_type(4)));
typedef float floatx4 __attribute__((ext_vector_type(4)));

#define DD 256
#define D4 64
#define KK 8192
#define NROWS 32768
#define BM 64            // rows per tile (stage-1)
#define BM2 32           // list-rows per stage-2 tile
#define BM4 128          // rows per tile (round-4 fallback)
#define NELEM 8388608
#define TAU1 1.25e-2f    // stage-1 margin (>6 sigma of 2e-3 rms pairwise fp16 err)
#define TAU2 2e-3f       // stage-2 margin
#define NSLICE 8
#define SLICE_K 1024
#define NVS 16           // stage-2 virtual slices
#define VS_K 512
#define NBLOCKS1 1024
#define TILES_PER_BLOCK 4

// ---- ws layout (bytes) ----
// 0        znorm (32768 f)      131072 cbnorm (8192 f)
// 163840   codes (32768 i32)    294912 loss partials (8192 f)
// 327680   cnt,cnt2             327696 list (32768 i32)
// 460800   list2 (32768 i32)
// 593920   pd (1MB)  1642496 ps (1MB)  2691072 pk (1MB)
// 4194304  bhi (4MB)  8388608 blo (4MB)
// 12582912 zg (16MB pre-swizzled z; reused post-stage1: pd2/ps2/pk2 2MB each)
#define WS_V9_BYTES      29360128
#define WS_CASCADE_BYTES 12582912
#define WS_SLICED2_BYTES 7800832
#define WS_R4_REFINE_BYTES 458768
#define WS_R4_FULL_BYTES   8849408

// combined norms (fallback paths)
__global__ __launch_bounds__(256) void norms_kernel(
    const float* __restrict__ z, const float* __restrict__ cb,
    float* __restrict__ znorm, float* __restrict__ cbnorm)
{
    int wave = threadIdx.x >> 6;
    int lane = threadIdx.x & 63;
    int row = blockIdx.x * 4 + wave;
    const float4* src;
    float* dst;
    int r;
    if (row < NROWS) { src = (const float4*)z;  dst = znorm;  r = row; }
    else             { src = (const float4*)cb; dst = cbnorm; r = row - NROWS; }
    float4 v = src[(size_t)r * D4 + lane];
    float s = v.x*v.x + v.y*v.y + v.z*v.z + v.w*v.w;
    #pragma unroll
    for (int off = 1; off < 64; off <<= 1) s += __shfl_xor(s, off);
    if (lane == 0) dst[r] = s;
}

// cb-only norms (main path) — bitwise-identical reduction to norms_kernel
__global__ __launch_bounds__(256) void cbnorm_kernel(
    const float* __restrict__ cb, float* __restrict__ cbnorm)
{
    int wave = threadIdx.x >> 6;
    int lane = threadIdx.x & 63;
    int r = blockIdx.x * 4 + wave;    // 0..8191
    float4 v = ((const float4*)cb)[(size_t)r * D4 + lane];
    float s = v.x*v.x + v.y*v.y + v.z*v.z + v.w*v.w;
    #pragma unroll
    for (int off = 1; off < 64; off <<= 1) s += __shfl_xor(s, off);
    if (lane == 0) cbnorm[r] = s;
}

// fp16 hi/lo planes of 16*cb
__global__ __launch_bounds__(256) void preconv_kernel(
    const float* __restrict__ cb, _Float16* __restrict__ bhi, _Float16* __restrict__ blo)
{
    size_t e4 = (size_t)blockIdx.x * 256 + threadIdx.x;
    float4 v = ((const float4*)cb)[e4];
    float t0 = v.x * 16.f, t1 = v.y * 16.f, t2 = v.z * 16.f, t3 = v.w * 16.f;
    _Float16 h0 = (_Float16)t0, h1 = (_Float16)t1, h2 = (_Float16)t2, h3 = (_Float16)t3;
    _Float16 l0 = (_Float16)((t0 - (float)h0) * 2048.f);
    _Float16 l1 = (_Float16)((t1 - (float)h1) * 2048.f);
    _Float16 l2 = (_Float16)((t2 - (float)h2) * 2048.f);
    _Float16 l3 = (_Float16)((t3 - (float)h3) * 2048.f);
    reinterpret_cast<half4*>(bhi)[e4] = half4{h0, h1, h2, h3};
    reinterpret_cast<half4*>(blo)[e4] = half4{l0, l1, l2, l3};
}

// z -> pre-swizzled fp16 tile image + fused znorm (row-constant -> argmin-safe)
__global__ __launch_bounds__(256) void preconv_z_kernel(
    const float* __restrict__ z, _Float16* __restrict__ zg, float* __restrict__ znorm)
{
    int gid = blockIdx.x * 256 + threadIdx.x;    // 0..1048575
    int row = gid >> 5;
    int g   = gid & 31;
    int r   = row & 63;
    const float4* src = (const float4*)z + (size_t)row * D4 + g * 2;
    float4 a = src[0], b = src[1];
    half8 h = { (_Float16)a.x, (_Float16)a.y, (_Float16)a.z, (_Float16)a.w,
                (_Float16)b.x, (_Float16)b.y, (_Float16)b.z, (_Float16)b.w };
    int gp = g ^ (r & 7);
    *reinterpret_cast<half8*>((char*)zg + (size_t)(row >> 6) * 32768 + r * 512 + gp * 16) = h;
    float s = a.x*a.x + a.y*a.y + a.z*a.z + a.w*a.w
            + b.x*b.x + b.y*b.y + b.z*b.z + b.w*b.w;
    #pragma unroll
    for (int off = 1; off < 32; off <<= 1) s += __shfl_xor(s, off);
    if ((threadIdx.x & 31) == 0) znorm[row] = s;
}

// ---------------- stage 1 (r11-exact): fp16 MFMA, static addressing, unroll-2 dc ----------------
__global__ __launch_bounds__(256, 4) void vq_fp16_v11(
    const _Float16* __restrict__ zg,
    const _Float16* __restrict__ bhip, const float* __restrict__ cbnorm,
    float* __restrict__ pd, float* __restrict__ ps, int* __restrict__ pk)
{
    __shared__ _Float16 zt[BM * DD];   // 32 KB (pre-swizzled image)

    const int tid  = threadIdx.x;
    const int lane = tid & 63;
    const int cg   = tid >> 6;
    const int l15  = lane & 15;
    const int lhi  = lane >> 4;
    const int slice = blockIdx.x & 7;
    const int grp   = blockIdx.x >> 3;

    const int A0 = l15 * 512 + ((lhi ^ (l15 & 3)) << 4) + (((l15 >> 2) & 1) << 6);
    int Ar[4];
    #pragma unroll
    for (int rf = 0; rf < 4; ++rf) Ar[rf] = A0 + rf * 8192;
    const char* zbase = (const char*)zt;

    const half8* bp = (const half8*)bhip + ((size_t)(slice * SLICE_K + cg * 32 + l15) * 32 + lhi);
    const float* cnp = cbnorm + slice * SLICE_K + cg * 32 + l15;
    const int kbase = slice * SLICE_K + cg * 32 + l15;

    #pragma unroll 1
    for (int j = 0; j < TILES_PER_BLOCK; ++j) {
        const int tileIdx = grp * TILES_PER_BLOCK + j;
        const int rowBase = tileIdx * BM;

        __syncthreads();
        {
            const float4* src = (const float4*)((const char*)zg + (size_t)tileIdx * 32768);
            float4* dst = (float4*)zt;
            #pragma unroll
            for (int i = 0; i < 8; ++i) dst[i * 256 + tid] = src[i * 256 + tid];
        }

        float bestd[4][4], secd[4][4];
        int   bestk[4][4];
        #pragma unroll
        for (int rf = 0; rf < 4; ++rf)
            #pragma unroll
            for (int reg = 0; reg < 4; ++reg) {
                bestd[rf][reg] = FLT_MAX; secd[rf][reg] = FLT_MAX; bestk[rf][reg] = 0;
            }

        __syncthreads();

        #pragma unroll 1
        for (int kt = 0; kt < SLICE_K / 128; ++kt) {
            floatx4 acc[4][2];
            #pragma unroll
            for (int rf = 0; rf < 4; ++rf)
                #pragma unroll
                for (int cf = 0; cf < 2; ++cf)
                    acc[rf][cf] = floatx4{0.f, 0.f, 0.f, 0.f};

            const half8* b0 = bp + kt * 4096;
            const half8* b1 = b0 + 512;

            #pragma unroll 2
            for (int dc = 0; dc < 8; ++dc) {
                half8 f0 = b0[dc * 4];
                half8 f1 = b1[dc * 4];
                #pragma unroll
                for (int rf = 0; rf < 4; ++rf) {
                    half8 a = *reinterpret_cast<const half8*>(zbase + (Ar[rf] ^ (dc << 6)));
                    acc[rf][0] = __builtin_amdgcn_mfma_f32_16x16x32_f16(a, f0, acc[rf][0], 0, 0, 0);
                    acc[rf][1] = __builtin_amdgcn_mfma_f32_16x16x32_f16(a, f1, acc[rf][1], 0, 0, 0);
                }
            }

            const float cn0 = cnp[kt * 128];
            const float cn1 = cnp[kt * 128 + 16];
            const int k0 = kbase + kt * 128;
            #pragma unroll
            for (int cf = 0; cf < 2; ++cf) {
                const float cn = cf ? cn1 : cn0;
                const int k = k0 + cf * 16;
                #pragma unroll
                for (int rf = 0; rf < 4; ++rf)
                    #pragma unroll
                    for (int reg = 0; reg < 4; ++reg) {
                        float m = fmaf(-0.125f, acc[rf][cf][reg], cn);
                        float w = fmaxf(bestd[rf][reg], m);
                        secd[rf][reg] = fminf(secd[rf][reg], w);
                        if (m < bestd[rf][reg]) { bestd[rf][reg] = m; bestk[rf][reg] = k; }
                    }
            }
        }

        #pragma unroll
        for (int off = 1; off < 16; off <<= 1) {
            #pragma unroll
            for (int rf = 0; rf < 4; ++rf)
                #pragma unroll
                for (int reg = 0; reg < 4; ++reg) {
                    float od = __shfl_xor(bestd[rf][reg], off);
                    int   ok = __shfl_xor(bestk[rf][reg], off);
                    float os = __shfl_xor(secd[rf][reg], off);
                    float hi = fmaxf(bestd[rf][reg], od);
                    secd[rf][reg] = fminf(fminf(secd[rf][reg], os), hi);
                    if (od < bestd[rf][reg] || (od == bestd[rf][reg] && ok < bestk[rf][reg])) {
                        bestd[rf][reg] = od; bestk[rf][reg] = ok;
                    }
                }
        }

        __syncthreads();
        float* dsc = reinterpret_cast<float*>(zt);
        int*   ksc = reinterpret_cast<int*>(zt) + 256;
        float* ssc = reinterpret_cast<float*>(zt) + 512;
        if (l15 == 0) {
            #pragma unroll
            for (int rf = 0; rf < 4; ++rf)
                #pragma unroll
                for (int reg = 0; reg < 4; ++reg) {
                    int rrow = rf * 16 + lhi * 4 + reg;
                    dsc[cg * 64 + rrow] = bestd[rf][reg];
                    ksc[cg * 64 + rrow] = bestk[rf][reg];
                    ssc[cg * 64 + rrow] = secd[rf][reg];
                }
        }
        __syncthreads();
        if (tid < 64) {
            float bd = dsc[tid];
            int   bk = ksc[tid];
            float sd = ssc[tid];
            #pragma unroll
            for (int c = 1; c < 4; ++c) {
                float od = dsc[c * 64 + tid];
                int   ok = ksc[c * 64 + tid];
                float os = ssc[c * 64 + tid];
                float hi = fmaxf(bd, od);
                sd = fminf(fminf(sd, os), hi);
                if (od < bd || (od == bd && ok < bk)) { bd = od; bk = ok; }
            }
            int row = rowBase + tid;
            pd[row * NSLICE + slice] = bd;
            ps[row * NSLICE + slice] = sd;
            pk[row * NSLICE + slice] = bk;
        }
    }
}

// r8 stage-1 fallback (reads raw z)
__global__ __launch_bounds__(256, 4) void vq_fp16_kernel(
    const float* __restrict__ z,
    const _Float16* __restrict__ bhip, const float* __restrict__ cbnorm,
    float* __restrict__ pd, float* __restrict__ ps, int* __restrict__ pk)
{
    __shared__ _Float16 zhi[BM * DD];
    const int tid  = threadIdx.x;
    const int lane = tid & 63;
    const int cg   = tid >> 6;
    const int l15  = lane & 15;
    const int lhi  = lane >> 4;
    const int slice = blockIdx.x & 7;
    const int grp   = blockIdx.x >> 3;
    const int sliceBase = slice * SLICE_K;

    int rowA[4];
    #pragma unroll
    for (int rf = 0; rf < 4; ++rf) rowA[rf] = rf * 16 + l15;

    #pragma unroll 1
    for (int j = 0; j < TILES_PER_BLOCK; ++j) {
        const int rowBase = (grp * TILES_PER_BLOCK + j) * BM;
        __syncthreads();
        #pragma unroll
        for (int i = 0; i < 16; ++i) {
            int gid = i * 256 + tid;
            int r   = gid >> 6;
            int c4  = gid & 63;
            float4 v = ((const float4*)z)[(size_t)(rowBase + r) * D4 + c4];
            _Float16 h0 = (_Float16)v.x, h1 = (_Float16)v.y,
                     h2 = (_Float16)v.z, h3 = (_Float16)v.w;
            int g = c4 >> 1;
            int byteOff = r * 512 + ((g ^ (r & 7)) << 4) + ((c4 & 1) << 3);
            *reinterpret_cast<half4*>(reinterpret_cast<char*>(zhi) + byteOff) = half4{h0, h1, h2, h3};
        }
        float bestd[4][4], secd[4][4];
        int   bestk[4][4];
        #pragma unroll
        for (int rf = 0; rf < 4; ++rf)
            #pragma unroll
            for (int reg = 0; reg < 4; ++reg) {
                bestd[rf][reg] = FLT_MAX; secd[rf][reg] = FLT_MAX; bestk[rf][reg] = 0;
            }
        __syncthreads();
        #pragma unroll 1
        for (int kt = 0; kt < SLICE_K / 128; ++kt) {
            floatx4 acc[4][2];
            #pragma unroll
            for (int rf = 0; rf < 4; ++rf)
                #pragma unroll
                for (int cf = 0; cf < 2; ++cf)
                    acc[rf][cf] = floatx4{0.f, 0.f, 0.f, 0.f};
            const int codeBase = sliceBase + kt * 128 + cg * 32 + l15;
            #pragma unroll 2
            for (int dc = 0; dc < 8; ++dc) {
                half8 bhi_f[2];
                #pragma unroll
                for (int cf = 0; cf < 2; ++cf) {
                    size_t off = (size_t)(codeBase + 16 * cf) * DD + dc * 32 + lhi * 8;
                    bhi_f[cf] = *reinterpret_cast<const half8*>(bhip + off);
                }
                #pragma unroll
                for (int rf = 0; rf < 4; ++rf) {
                    int g = dc * 4 + lhi;
                    int off = rowA[rf] * 512 + ((g ^ (rowA[rf] & 7)) << 4);
                    half8 ahi = *reinterpret_cast<const half8*>(reinterpret_cast<const char*>(zhi) + off);
                    #pragma unroll
                    for (int cf = 0; cf < 2; ++cf)
                        acc[rf][cf] = __builtin_amdgcn_mfma_f32_16x16x32_f16(ahi, bhi_f[cf], acc[rf][cf], 0, 0, 0);
                }
            }
            #pragma unroll
            for (int cf = 0; cf < 2; ++cf) {
                int k = codeBase + 16 * cf;
                float cn = cbnorm[k];
                #pragma unroll
                for (int rf = 0; rf < 4; ++rf)
                    #pragma unroll
                    for (int reg = 0; reg < 4; ++reg) {
                        float m = fmaf(-0.125f, acc[rf][cf][reg], cn);
                        float w = fmaxf(bestd[rf][reg], m);
                        secd[rf][reg] = fminf(secd[rf][reg], w);
                        if (m < bestd[rf][reg]) { bestd[rf][reg] = m; bestk[rf][reg] = k; }
                    }
            }
        }
        #pragma unroll
        for (int off = 1; off < 16; off <<= 1) {
            #pragma unroll
            for (int rf = 0; rf < 4; ++rf)
                #pragma unroll
                for (int reg = 0; reg < 4; ++reg) {
                    float od = __shfl_xor(bestd[rf][reg], off);
                    int   ok = __shfl_xor(bestk[rf][reg], off);
                    float os = __shfl_xor(secd[rf][reg], off);
                    float hi = fmaxf(bestd[rf][reg], od);
                    secd[rf][reg] = fminf(fminf(secd[rf][reg], os), hi);
                    if (od < bestd[rf][reg] || (od == bestd[rf][reg] && ok < bestk[rf][reg])) {
                        bestd[rf][reg] = od; bestk[rf][reg] = ok;
                    }
                }
        }
        __syncthreads();
        float* dsc = reinterpret_cast<float*>(zhi);
        int*   ksc = reinterpret_cast<int*>(zhi) + 256;
        float* ssc = reinterpret_cast<float*>(zhi) + 512;
        if (l15 == 0) {
            #pragma unroll
            for (int rf = 0; rf < 4; ++rf)
                #pragma unroll
                for (int reg = 0; reg < 4; ++reg) {
                    int rrow = rf * 16 + lhi * 4 + reg;
                    dsc[cg * 64 + rrow] = bestd[rf][reg];
                    ksc[cg * 64 + rrow] = bestk[rf][reg];
                    ssc[cg * 64 + rrow] = secd[rf][reg];
                }
        }
        __syncthreads();
        if (tid < 64) {
            float bd = dsc[tid];
            int   bk = ksc[tid];
            float sd = ssc[tid];
            #pragma unroll
            for (int c = 1; c < 4; ++c) {
                float od = dsc[c * 64 + tid];
                int   ok = ksc[c * 64 + tid];
                float os = ssc[c * 64 + tid];
                float hi = fmaxf(bd, od);
                sd = fminf(fminf(sd, os), hi);
                if (od < bd || (od == bd && ok < bk)) { bd = od; bk = ok; }
            }
            int row = rowBase + tid;
            pd[row * NSLICE + slice] = bd;
            ps[row * NSLICE + slice] = sd;
            pk[row * NSLICE + slice] = bk;
        }
    }
}

__global__ __launch_bounds__(256) void slice_reduce_kernel(
    const float* __restrict__ pd, const float* __restrict__ ps, const int* __restrict__ pk,
    int* __restrict__ codes, float* __restrict__ codes_f,
    int* __restrict__ cnt, int* __restrict__ list, float tau)
{
    int row = blockIdx.x * 256 + threadIdx.x;
    float bd = FLT_MAX, sd = FLT_MAX;
    int bk = 0;
    #pragma unroll
    for (int s = 0; s < NSLICE; ++s) {
        float d  = pd[row * NSLICE + s];
        int   k  = pk[row * NSLICE + s];
        float s2 = ps[row * NSLICE + s];
        float hi = fmaxf(bd, d);
        sd = fminf(fminf(sd, s2), hi);
        if (d < bd || (d == bd && k < bk)) { bd = d; bk = k; }
    }
    codes[row]   = bk;
    codes_f[row] = (float)bk;
    if ((sd - bd) < tau) {
        int idx = atomicAdd(cnt, 1);
        list[idx] = row;
    }
}

// stage 2: hi/lo MFMA rescan of flagged rows, 16 virtual slices of 512 codes
__global__ __launch_bounds__(256, 4) void vq_refine2_kernel(
    const float* __restrict__ z,
    const _Float16* __restrict__ bhip, const _Float16* __restrict__ blop,
    const float* __restrict__ cbnorm,
    const int* __restrict__ cnt, const int* __restrict__ list,
    float* __restrict__ pd2, float* __restrict__ ps2, int* __restrict__ pk2)
{
    __shared__ _Float16 zhi[BM2 * DD];
    __shared__ _Float16 zlo[BM2 * DD];

    const int n1 = *cnt;
    if (n1 == 0) return;
    const int ntiles = (n1 + BM2 - 1) / BM2;
    const int njobs = ntiles * NVS;

    const int tid  = threadIdx.x;
    const int lane = tid & 63;
    const int cg   = tid >> 6;
    const int l15  = lane & 15;
    const int lhi  = lane >> 4;

    int rowA[2];
    #pragma unroll
    for (int rf = 0; rf < 2; ++rf) rowA[rf] = rf * 16 + l15;

    for (int job = blockIdx.x; job < njobs; job += gridDim.x) {
        const int vs    = job & (NVS - 1);
        const int tile  = job >> 4;
        const int base  = tile * BM2;
        const int vsBase = vs * VS_K;

        __syncthreads();
        #pragma unroll
        for (int i = 0; i < 8; ++i) {
            int gid = i * 256 + tid;
            int r   = gid >> 6;
            int c4  = gid & 63;
            int pos = base + r;
            int row = list[pos < n1 ? pos : (n1 - 1)];
            float4 v = ((const float4*)z)[(size_t)row * D4 + c4];
            _Float16 h0 = (_Float16)v.x, h1 = (_Float16)v.y,
                     h2 = (_Float16)v.z, h3 = (_Float16)v.w;
            _Float16 e0 = (_Float16)((v.x - (float)h0) * 2048.f);
            _Float16 e1 = (_Float16)((v.y - (float)h1) * 2048.f);
            _Float16 e2 = (_Float16)((v.z - (float)h2) * 2048.f);
            _Float16 e3 = (_Float16)((v.w - (float)h3) * 2048.f);
            int g = c4 >> 1;
            int byteOff = r * 512 + ((g ^ (r & 7)) << 4) + ((c4 & 1) << 3);
            *reinterpret_cast<half4*>(reinterpret_cast<char*>(zhi) + byteOff) = half4{h0, h1, h2, h3};
            *reinterpret_cast<half4*>(reinterpret_cast<char*>(zlo) + byteOff) = half4{e0, e1, e2, e3};
        }

        float bestd[2][4], secd[2][4];
        int   bestk[2][4];
        #pragma unroll
        for (int rf = 0; rf < 2; ++rf)
            #pragma unroll
            for (int reg = 0; reg < 4; ++reg) {
                bestd[rf][reg] = FLT_MAX; secd[rf][reg] = FLT_MAX; bestk[rf][reg] = 0;
            }

        __syncthreads();

        #pragma unroll 1
        for (int kt = 0; kt < VS_K / 128; ++kt) {   // 4 steps of 128 codes
            floatx4 accH[2][2], accM[2][2];
            #pragma unroll
            for (int rf = 0; rf < 2; ++rf)
                #pragma unroll
                for (int cf = 0; cf < 2; ++cf) {
                    accH[rf][cf] = floatx4{0.f, 0.f, 0.f, 0.f};
                    accM[rf][cf] = floatx4{0.f, 0.f, 0.f, 0.f};
                }
            const int codeBase = vsBase + kt * 128 + cg * 32 + l15;
            #pragma unroll 2
            for (int dc = 0; dc < 8; ++dc) {
                half8 bhi_f[2], blo_f[2];
                #pragma unroll
                for (int cf = 0; cf < 2; ++cf) {
                    size_t off = (size_t)(codeBase + 16 * cf) * DD + dc * 32 + lhi * 8;
                    bhi_f[cf] = *reinterpret_cast<const half8*>(bhip + off);
                    blo_f[cf] = *reinterpret_cast<const half8*>(blop + off);
                }
                #pragma unroll
                for (int rf = 0; rf < 2; ++rf) {
                    int g = dc * 4 + lhi;
                    int off = rowA[rf] * 512 + ((g ^ (rowA[rf] & 7)) << 4);
                    half8 ahi = *reinterpret_cast<const half8*>(reinterpret_cast<const char*>(zhi) + off);
                    half8 alo = *reinterpret_cast<const half8*>(reinterpret_cast<const char*>(zlo) + off);
                    #pragma unroll
                    for (int cf = 0; cf < 2; ++cf) {
                        accH[rf][cf] = __builtin_amdgcn_mfma_f32_16x16x32_f16(ahi, bhi_f[cf], accH[rf][cf], 0, 0, 0);
                        accM[rf][cf] = __builtin_amdgcn_mfma_f32_16x16x32_f16(alo, bhi_f[cf], accM[rf][cf], 0, 0, 0);
                        accM[rf][cf] = __builtin_amdgcn_mfma_f32_16x16x32_f16(ahi, blo_f[cf], accM[rf][cf], 0, 0, 0);
                    }
                }
            }
            #pragma unroll
            for (int cf = 0; cf < 2; ++cf) {
                int k = codeBase + 16 * cf;
                float cn = cbnorm[k];
                #pragma unroll
                for (int rf = 0; rf < 2; ++rf)
                    #pragma unroll
                    for (int reg = 0; reg < 4; ++reg) {
                        float dot16 = fmaf(accM[rf][cf][reg], 0x1p-11f, accH[rf][cf][reg]);
                        float m = fmaf(-0.125f, dot16, cn);
                        float w = fmaxf(bestd[rf][reg], m);
                        secd[rf][reg] = fminf(secd[rf][reg], w);
                        if (m < bestd[rf][reg]) { bestd[rf][reg] = m; bestk[rf][reg] = k; }
                    }
            }
        }

        #pragma unroll
        for (int off = 1; off < 16; off <<= 1) {
            #pragma unroll
            for (int rf = 0; rf < 2; ++rf)
                #pragma unroll
                for (int reg = 0; reg < 4; ++reg) {
                    float od = __shfl_xor(bestd[rf][reg], off);
                    int   ok = __shfl_xor(bestk[rf][reg], off);
                    float os = __shfl_xor(secd[rf][reg], off);
                    float hi = fmaxf(bestd[rf][reg], od);
                    secd[rf][reg] = fminf(fminf(secd[rf][reg], os), hi);
                    if (od < bestd[rf][reg] || (od == bestd[rf][reg] && ok < bestk[rf][reg])) {
                        bestd[rf][reg] = od; bestk[rf][reg] = ok;
                    }
                }
        }

        __syncthreads();
        float* dsc = reinterpret_cast<float*>(zhi);
        int*   ksc = reinterpret_cast<int*>(zhi) + 128;
        float* ssc = reinterpret_cast<float*>(zhi) + 256;
        if (l15 == 0) {
            #pragma unroll
            for (int rf = 0; rf < 2; ++rf)
                #pragma unroll
                for (int reg = 0; reg < 4; ++reg) {
                    int rrow = rf * 16 + lhi * 4 + reg;
                    dsc[cg * 32 + rrow] = bestd[rf][reg];
                    ksc[cg * 32 + rrow] = bestk[rf][reg];
                    ssc[cg * 32 + rrow] = secd[rf][reg];
                }
        }
        __syncthreads();
        if (tid < 32) {
            float bd = dsc[tid];
            int   bk = ksc[tid];
            float sd = ssc[tid];
            #pragma unroll
            for (int c = 1; c < 4; ++c) {
                float od = dsc[c * 32 + tid];
                int   ok = ksc[c * 32 + tid];
                float os = ssc[c * 32 + tid];
                float hi = fmaxf(bd, od);
                sd = fminf(fminf(sd, os), hi);
                if (od < bd || (od == bd && ok < bk)) { bd = od; bk = ok; }
            }
            int pos = base + tid;
            pd2[pos * NVS + vs] = bd;
            ps2[pos * NVS + vs] = sd;
            pk2[pos * NVS + vs] = bk;
        }
    }
}

__global__ __launch_bounds__(256) void slice_reduce2_kernel(
    const float* __restrict__ pd2, const float* __restrict__ ps2, const int* __restrict__ pk2,
    const int* __restrict__ cnt, const int* __restrict__ list,
    int* __restrict__ codes, float* __restrict__ codes_f,
    int* __restrict__ cnt2, int* __restrict__ list2)
{
    const int n1 = *cnt;
    for (int i = blockIdx.x * 256 + threadIdx.x; i < n1; i += gridDim.x * 256) {
        float bd = FLT_MAX, sd = FLT_MAX;
        int bk = 0;
        #pragma unroll
        for (int s = 0; s < NVS; ++s) {
            float d  = pd2[i * NVS + s];
            int   k  = pk2[i * NVS + s];
            float s2 = ps2[i * NVS + s];
            float hi = fmaxf(bd, d);
            sd = fminf(fminf(sd, s2), hi);
            if (d < bd || (d == bd && k < bk)) { bd = d; bk = k; }
        }
        int row = list[i];
        codes[row]   = bk;
        codes_f[row] = (float)bk;
        if ((sd - bd) < TAU2) {
            int idx = atomicAdd(cnt2, 1);
            list2[idx] = row;
        }
    }
}

// stage 3 / fallback: per-row exact fp32 re-argmin (round-1 numerics)
__global__ __launch_bounds__(256) void refine_kernel(
    const float* __restrict__ z, const float* __restrict__ cb,
    const float* __restrict__ znorm, const float* __restrict__ cbnorm,
    const int* __restrict__ cnt, const int* __restrict__ list,
    int* __restrict__ codes, float* __restrict__ codes_f)
{
    __shared__ float zrow[DD];
    __shared__ float dred[4];
    __shared__ int   kred[4];
    const int tid = threadIdx.x;
    const int lane = tid & 63;
    const int wv = tid >> 6;
    const int n = *cnt;
    for (int i = blockIdx.x; i < n; i += gridDim.x) {
        const int row = list[i];
        if (tid < 64) ((float4*)zrow)[tid] = ((const float4*)z)[(size_t)row * D4 + tid];
        const float zn = znorm[row];
        __syncthreads();
        float bd = FLT_MAX;
        int   bk = 0;
        for (int k = tid; k < KK; k += 256) {
            const float4* crow = (const float4*)cb + (size_t)k * D4;
            float acc = 0.f;
            #pragma unroll 8
            for (int d4 = 0; d4 < D4; ++d4) {
                float4 c = crow[d4];
                float4 zv = ((const float4*)zrow)[d4];
                acc = fmaf(zv.x, c.x, acc);
                acc = fmaf(zv.y, c.y, acc);
                acc = fmaf(zv.z, c.z, acc);
                acc = fmaf(zv.w, c.w, acc);
            }
            float dist = fmaf(-2.f, acc, zn) + cbnorm[k];
            if (dist < bd) { bd = dist; bk = k; }
        }
        #pragma unroll
        for (int off = 1; off < 64; off <<= 1) {
            float od = __shfl_xor(bd, off);
            int   ok = __shfl_xor(bk, off);
            if (od < bd || (od == bd && ok < bk)) { bd = od; bk = ok; }
        }
        if (lane == 0) { dred[wv] = bd; kred[wv] = bk; }
        __syncthreads();
        if (tid == 0) {
            #pragma unroll
            for (int c = 1; c < 4; ++c) {
                if (dred[c] < bd || (dred[c] == bd && kred[c] < bk)) { bd = dred[c]; bk = kred[c]; }
            }
            codes[row]   = bk;
            codes_f[row] = (float)bk;
        }
        __syncthreads();
    }
}

__global__ __launch_bounds__(256) void gather_loss_kernel(
    const float* __restrict__ z, const float* __restrict__ cb,
    const int* __restrict__ codes, float* __restrict__ zq_out,
    float* __restrict__ partials)
{
    __shared__ float red[4];
    int tid = threadIdx.x;
    size_t e4 = (size_t)blockIdx.x * 256 + tid;
    int row = (int)(e4 >> 6);
    int d4  = (int)(e4 & 63);
    int code = codes[row];
    float4 q  = ((const float4*)cb)[(size_t)code * D4 + d4];
    float4 zv = ((const float4*)z)[e4];
    float dx = q.x - zv.x, dy = q.y - zv.y, dz = q.z - zv.z, dw = q.w - zv.w;
    float4 o;
    o.x = zv.x + dx; o.y = zv.y + dy; o.z = zv.z + dz; o.w = zv.w + dw;
    ((float4*)zq_out)[e4] = o;
    float s = dx*dx + dy*dy + dz*dz + dw*dw;
    #pragma unroll
    for (int off = 1; off < 64; off <<= 1) s += __shfl_xor(s, off);
    if ((tid & 63) == 0) red[tid >> 6] = s;
    __syncthreads();
    if (tid == 0) partials[blockIdx.x] = ((red[0] + red[1]) + red[2]) + red[3];
}

__global__ __launch_bounds__(256) void final_loss_kernel(
    const float* __restrict__ partials, float* __restrict__ out_loss)
{
    __shared__ float red[4];
    int tid = threadIdx.x;
    float s = 0.f;
    #pragma unroll 4
    for (int i = 0; i < 32; ++i) s += partials[tid * 32 + i];
    #pragma unroll
    for (int off = 1; off < 64; off <<= 1) s += __shfl_xor(s, off);
    if ((tid & 63) == 0) red[tid >> 6] = s;
    __syncthreads();
    if (tid == 0) {
        float tot = ((red[0] + red[1]) + red[2]) + red[3];
        out_loss[0] = 0.5f * (tot / (float)NELEM);
    }
}

// round-4 fallback kernel (tiny-ws path, proven)
template <bool PRECONV, bool REFINE>
__global__ __launch_bounds__(512, 1) void vq_mfma_kernel(
    const float* __restrict__ z, const float* __restrict__ cb,
    const _Float16* __restrict__ bhip, const _Float16* __restrict__ blop,
    const float* __restrict__ znorm, const float* __restrict__ cbnorm,
    int* __restrict__ codes, float* __restrict__ codes_f,
    int* __restrict__ cnt, int* __restrict__ list)
{
    __shared__ _Float16 zhi[BM4 * DD];
    __shared__ _Float16 zlo[BM4 * DD];
    const int tid  = threadIdx.x;
    const int lane = tid & 63;
    const int w    = tid >> 6;
    const int rg   = w >> 2;
    const int cg   = w & 3;
    const int l15  = lane & 15;
    const int lhi  = lane >> 4;
    const int rowBase = blockIdx.x * BM4;

    #pragma unroll
    for (int i = 0; i < 16; ++i) {
        int gid = i * 512 + tid;
        int r   = gid >> 6;
        int c4  = gid & 63;
        float4 v = ((const float4*)z)[(size_t)(rowBase + r) * D4 + c4];
        _Float16 h0 = (_Float16)v.x, h1 = (_Float16)v.y,
                 h2 = (_Float16)v.z, h3 = (_Float16)v.w;
        _Float16 e0 = (_Float16)((v.x - (float)h0) * 2048.f);
        _Float16 e1 = (_Float16)((v.y - (float)h1) * 2048.f);
        _Float16 e2 = (_Float16)((v.z - (float)h2) * 2048.f);
        _Float16 e3 = (_Float16)((v.w - (float)h3) * 2048.f);
        int g = c4 >> 1;
        int byteOff = r * 512 + (((g ^ (r & 7))) << 4) + ((c4 & 1) << 3);
        *reinterpret_cast<half4*>(reinterpret_cast<char*>(zhi) + byteOff) = half4{h0, h1, h2, h3};
        *reinterpret_cast<half4*>(reinterpret_cast<char*>(zlo) + byteOff) = half4{e0, e1, e2, e3};
    }
    int rowA[4];
    #pragma unroll
    for (int rf = 0; rf < 4; ++rf) rowA[rf] = rg * 64 + rf * 16 + l15;
    float zn[4][4];
    #pragma unroll
    for (int rf = 0; rf < 4; ++rf)
        #pragma unroll
        for (int reg = 0; reg < 4; ++reg)
            zn[rf][reg] = znorm[rowBase + rg * 64 + rf * 16 + lhi * 4 + reg];
    float bestd[4][4], secd[4][4];
    int   bestk[4][4];
    #pragma unroll
    for (int rf = 0; rf < 4; ++rf)
        #pragma unroll
        for (int reg = 0; reg < 4; ++reg) {
            bestd[rf][reg] = FLT_MAX; secd[rf][reg] = FLT_MAX; bestk[rf][reg] = 0;
        }
    __syncthreads();
    for (int kt = 0; kt < KK / 256; ++kt) {
        floatx4 accH[4][4], accM[4][4];
        #pragma unroll
        for (int rf = 0; rf < 4; ++rf)
            #pragma unroll
            for (int cf = 0; cf < 4; ++cf) {
                accH[rf][cf] = floatx4{0.f, 0.f, 0.f, 0.f};
                accM[rf][cf] = floatx4{0.f, 0.f, 0.f, 0.f};
            }
        const int codeBase = kt * 256 + cg * 64 + l15;
        for (int dc = 0; dc < 8; ++dc) {
            half8 bhi_f[4], blo_f[4];
            #pragma unroll
            for (int cf = 0; cf < 4; ++cf) {
                if (PRECONV) {
                    size_t off = (size_t)(codeBase + 16 * cf) * DD + dc * 32 + lhi * 8;
                    bhi_f[cf] = *reinterpret_cast<const half8*>(bhip + off);
                    blo_f[cf] = *reinterpret_cast<const half8*>(blop + off);
                } else {
                    const float4* p = (const float4*)(cb + (size_t)(codeBase + 16 * cf) * DD + dc * 32 + lhi * 8);
                    float4 u0 = p[0];
                    float4 u1 = p[1];
                    float uv[8] = {u0.x, u0.y, u0.z, u0.w, u1.x, u1.y, u1.z, u1.w};
                    half8 bh, bl;
                    #pragma unroll
                    for (int jj = 0; jj < 8; ++jj) {
                        float t = uv[jj] * 16.f;
                        _Float16 h = (_Float16)t;
                        bh[jj] = h;
                        bl[jj] = (_Float16)((t - (float)h) * 2048.f);
                    }
                    bhi_f[cf] = bh; blo_f[cf] = bl;
                }
            }
            #pragma unroll
            for (int rf = 0; rf < 4; ++rf) {
                int g = dc * 4 + lhi;
                int off = rowA[rf] * 512 + ((g ^ (rowA[rf] & 7)) << 4);
                half8 ahi = *reinterpret_cast<const half8*>(reinterpret_cast<const char*>(zhi) + off);
                half8 alo = *reinterpret_cast<const half8*>(reinterpret_cast<const char*>(zlo) + off);
                #pragma unroll
                for (int cf = 0; cf < 4; ++cf) {
                    accH[rf][cf] = __builtin_amdgcn_mfma_f32_16x16x32_f16(ahi, bhi_f[cf], accH[rf][cf], 0, 0, 0);
                    accM[rf][cf] = __builtin_amdgcn_mfma_f32_16x16x32_f16(alo, bhi_f[cf], accM[rf][cf], 0, 0, 0);
                    accM[rf][cf] = __builtin_amdgcn_mfma_f32_16x16x32_f16(ahi, blo_f[cf], accM[rf][cf], 0, 0, 0);
                }
            }
        }
        #pragma unroll
        for (int cf = 0; cf < 4; ++cf) {
            int k = codeBase + 16 * cf;
            float cn = cbnorm[k];
            #pragma unroll
            for (int rf = 0; rf < 4; ++rf)
                #pragma unroll
                for (int reg = 0; reg < 4; ++reg) {
                    float dot16 = fmaf(accM[rf][cf][reg], 0x1p-11f, accH[rf][cf][reg]);
                    float dist  = fmaf(-0.125f, dot16, zn[rf][reg]) + cn;
                    float wv2 = fmaxf(bestd[rf][reg], dist);
                    secd[rf][reg] = fminf(secd[rf][reg], wv2);
                    if (dist < bestd[rf][reg]) { bestd[rf][reg] = dist; bestk[rf][reg] = k; }
                }
        }
    }
    #pragma unroll
    for (int off = 1; off < 16; off <<= 1) {
        #pragma unroll
        for (int rf = 0; rf < 4; ++rf)
            #pragma unroll
            for (int reg = 0; reg < 4; ++reg) {
                float od = __shfl_xor(bestd[rf][reg], off);
                int   ok = __shfl_xor(bestk[rf][reg], off);
                float os = __shfl_xor(secd[rf][reg], off);
                float hi = fmaxf(bestd[rf][reg], od);
                secd[rf][reg] = fminf(fminf(secd[rf][reg], os), hi);
                if (od < bestd[rf][reg] || (od == bestd[rf][reg] && ok < bestk[rf][reg])) {
                    bestd[rf][reg] = od; bestk[rf][reg] = ok;
                }
            }
    }
    __syncthreads();
    float* dsc = reinterpret_cast<float*>(zhi);
    int*   ksc = reinterpret_cast<int*>(zhi) + 512;
    float* ssc = reinterpret_cast<float*>(zhi) + 1024;
    if (l15 == 0) {
        #pragma unroll
        for (int rf = 0; rf < 4; ++rf)
            #pragma unroll
            for (int reg = 0; reg < 4; ++reg) {
                int rrow = rg * 64 + rf * 16 + lhi * 4 + reg;
                dsc[cg * 128 + rrow] = bestd[rf][reg];
                ksc[cg * 128 + rrow] = bestk[rf][reg];
                ssc[cg * 128 + rrow] = secd[rf][reg];
            }
    }
    __syncthreads();
    if (tid < 128) {
        float bd = dsc[tid];
        int   bk = ksc[tid];
        float sd = ssc[tid];
        #pragma unroll
        for (int c = 1; c < 4; ++c) {
            float od = dsc[c * 128 + tid];
            int   ok = ksc[c * 128 + tid];
            float os = ssc[c * 128 + tid];
            float hi = fmaxf(bd, od);
            sd = fminf(fminf(sd, os), hi);
            if (od < bd || (od == bd && ok < bk)) { bd = od; bk = ok; }
        }
        int row = rowBase + tid;
        codes[row]   = bk;
        codes_f[row] = (float)bk;
        if (REFINE && (sd - bd) < TAU2) {
            int idx = atomicAdd(cnt, 1);
            list[idx] = row;
        }
    }
}

extern "C" void kernel_launch(void* const* d_in, const int* in_sizes, int n_in,
                              void* d_out, int out_size, void* d_ws, size_t ws_size,
                              hipStream_t stream) {
    const float* z  = (const float*)d_in[0];
    const float* cb = (const float*)d_in[1];
    float* out      = (float*)d_out;
    float* zq_out   = out;
    float* loss_out = out + NELEM;
    float* codes_f  = out + NELEM + 1;

    char* wsb       = (char*)d_ws;
    float* znorm    = (float*)(wsb + 0);
    float* cbnorm   = (float*)(wsb + 131072);
    int*   codes    = (int*)(wsb + 163840);
    float* partials = (float*)(wsb + 294912);
    int*   cnt      = (int*)(wsb + 327680);
    int*   cnt2     = (int*)(wsb + 327684);
    int*   list     = (int*)(wsb + 327696);

    if (ws_size >= (size_t)WS_V9_BYTES) {
        int*   list2  = (int*)(wsb + 460800);
        float* pd     = (float*)(wsb + 593920);
        float* ps     = (float*)(wsb + 1642496);
        int*   pk     = (int*)(wsb + 2691072);
        _Float16* bhi = (_Float16*)(wsb + 4194304);
        _Float16* blo = (_Float16*)(wsb + 8388608);
        _Float16* zg  = (_Float16*)(wsb + 12582912);
        // stage-2 partials reuse the zg region (zg dead after stage-1)
        float* pd2    = (float*)(wsb + 12582912);
        float* ps2    = (float*)(wsb + 12582912 + 2097152);
        int*   pk2    = (int*)(wsb + 12582912 + 4194304);

        hipMemsetAsync(cnt, 0, 8, stream);
        cbnorm_kernel<<<2048, 256, 0, stream>>>(cb, cbnorm);
        preconv_kernel<<<2048, 256, 0, stream>>>(cb, bhi, blo);
        preconv_z_kernel<<<4096, 256, 0, stream>>>(z, zg, znorm);
        vq_fp16_v11<<<NBLOCKS1, 256, 0, stream>>>(zg, bhi, cbnorm, pd, ps, pk);
        slice_reduce_kernel<<<128, 256, 0, stream>>>(pd, ps, pk, codes, codes_f, cnt, list, TAU1);
        vq_refine2_kernel<<<512, 256, 0, stream>>>(z, bhi, blo, cbnorm, cnt, list, pd2, ps2, pk2);
        slice_reduce2_kernel<<<64, 256, 0, stream>>>(pd2, ps2, pk2, cnt, list, codes, codes_f, cnt2, list2);
        refine_kernel<<<256, 256, 0, stream>>>(z, cb, znorm, cbnorm, cnt2, list2, codes, codes_f);
    } else if (ws_size >= (size_t)WS_CASCADE_BYTES) {
        int*   list2  = (int*)(wsb + 460800);
        float* pd     = (float*)(wsb + 593920);
        float* ps     = (float*)(wsb + 1642496);
        int*   pk     = (int*)(wsb + 2691072);
        _Float16* bhi = (_Float16*)(wsb + 4194304);
        _Float16* blo = (_Float16*)(wsb + 8388608);
        hipMemsetAsync(cnt, 0, 8, stream);
        norms_kernel<<<10240, 256, 0, stream>>>(z, cb, znorm, cbnorm);
        preconv_kernel<<<2048, 256, 0, stream>>>(cb, bhi, blo);
        vq_fp16_kernel<<<NBLOCKS1, 256, 0, stream>>>(z, bhi, cbnorm, pd, ps, pk);
        slice_reduce_kernel<<<128, 256, 0, stream>>>(pd, ps, pk, codes, codes_f, cnt, list, TAU1);
        // stage-2 full-width fallback: reuse pd/ps/pk with NSLICE granularity via refine_kernel directly
        refine_kernel<<<256, 256, 0, stream>>>(z, cb, znorm, cbnorm, cnt, list, codes, codes_f);
    } else {
        _Float16* bhi = (_Float16*)(wsb + 460800);
        _Float16* blo = (_Float16*)(wsb + 4655104);
        const bool preconv = ws_size >= (size_t)WS_R4_FULL_BYTES;
        const bool refine  = ws_size >= (size_t)WS_R4_REFINE_BYTES;
        norms_kernel<<<10240, 256, 0, stream>>>(z, cb, znorm, cbnorm);
        if (refine) hipMemsetAsync(cnt, 0, sizeof(int), stream);
        if (preconv) preconv_kernel<<<2048, 256, 0, stream>>>(cb, bhi, blo);
        if (preconv && refine)
            vq_mfma_kernel<true, true><<<NROWS / BM4, 512, 0, stream>>>(z, cb, bhi, blo, znorm, cbnorm, codes, codes_f, cnt, list);
        else if (preconv)
            vq_mfma_kernel<true, false><<<NROWS / BM4, 512, 0, stream>>>(z, cb, bhi, blo, znorm, cbnorm, codes, codes_f, cnt, list);
        else if (refine)
            vq_mfma_kernel<false, true><<<NROWS / BM4, 512, 0, stream>>>(z, cb, bhi, blo, znorm, cbnorm, codes, codes_f, cnt, list);
        else
            vq_mfma_kernel<false, false><<<NROWS / BM4, 512, 0, stream>>>(z, cb, bhi, blo, znorm, cbnorm, codes, codes_f, cnt, list);
        if (refine)
            refine_kernel<<<256, 256, 0, stream>>>(z, cb, znorm, cbnorm, cnt, list, codes, codes_f);
    }

    gather_loss_kernel<<<8192, 256, 0, stream>>>(z, cb, codes, zq_out, partials);
    final_loss_kernel<<<1, 256, 0, stream>>>(partials, loss_out);
}

// Round 15
// 578.776 us; speedup vs baseline: 1.1102x; 1.0282x over previous
//
#include <hip/hip_runtime.h>
#include <hip/hip_fp16.h>
#include <float.h>

typedef _Float16 half8 __attribute__((ext_vector_type(8)));
typedef _Float16 half4 __attribute__((ext_vector_type(4)));
typedef float floatx4 __attribute__((ext_vector_type(4)));

#define DD 256
#define D4 64
#define KK 8192
#define NROWS 32768
#define BM 64            // rows per tile (stage-1)
#define BM2 32           // list-rows per refine tile
#define BM4 128          // rows per tile (round-4 fallback)
#define NELEM 8388608
#define TAU1 1.25e-2f    // stage-1 margin (>6 sigma of fp16-path err)
#define NSLICE 8
#define SLICE_K 1024
#define NBLOCKS1 1024
#define TILES_PER_BLOCK 4
#define TAU2 2e-3f       // fallback-path stage margin

// ---- ws layout (bytes) ----
// 0        znorm (32768 f)      131072 cbnorm (8192 f)
// 163840   codes (32768 i32)    294912 loss partials (8192 f)
// 327680   cnt,cnt2             327696 list (32768 i32)
// 460800   list2 (32768 i32)
// 593920   pd (1MB)  1642496 ps (1MB)  2691072 pk (1MB)
// 4194304  bhi (4MB)  8388608 blo (4MB, fallback only)
// 12582912 zg (16MB pre-swizzled z; reused post-stage1: pd2 1MB, pk2 1MB)
#define WS_V9_BYTES      29360128
#define WS_CASCADE_BYTES 12582912
#define WS_R4_REFINE_BYTES 458768
#define WS_R4_FULL_BYTES   8849408

// combined norms (fallback paths)
__global__ __launch_bounds__(256) void norms_kernel(
    const float* __restrict__ z, const float* __restrict__ cb,
    float* __restrict__ znorm, float* __restrict__ cbnorm)
{
    int wave = threadIdx.x >> 6;
    int lane = threadIdx.x & 63;
    int row = blockIdx.x * 4 + wave;
    const float4* src;
    float* dst;
    int r;
    if (row < NROWS) { src = (const float4*)z;  dst = znorm;  r = row; }
    else             { src = (const float4*)cb; dst = cbnorm; r = row - NROWS; }
    float4 v = src[(size_t)r * D4 + lane];
    float s = v.x*v.x + v.y*v.y + v.z*v.z + v.w*v.w;
    #pragma unroll
    for (int off = 1; off < 64; off <<= 1) s += __shfl_xor(s, off);
    if (lane == 0) dst[r] = s;
}

// main path: cbnorm (bitwise-identical reduction) + bhi plane in one cb pass
__global__ __launch_bounds__(256) void prep_cb_kernel(
    const float* __restrict__ cb, float* __restrict__ cbnorm, _Float16* __restrict__ bhi)
{
    int wave = threadIdx.x >> 6;
    int lane = threadIdx.x & 63;
    int r = blockIdx.x * 4 + wave;    // 0..8191
    float4 v = ((const float4*)cb)[(size_t)r * D4 + lane];
    // bhi = f16(16*c)
    _Float16 h0 = (_Float16)(v.x * 16.f), h1 = (_Float16)(v.y * 16.f);
    _Float16 h2 = (_Float16)(v.z * 16.f), h3 = (_Float16)(v.w * 16.f);
    reinterpret_cast<half4*>(bhi)[(size_t)r * D4 + lane] = half4{h0, h1, h2, h3};
    float s = v.x*v.x + v.y*v.y + v.z*v.z + v.w*v.w;
    #pragma unroll
    for (int off = 1; off < 64; off <<= 1) s += __shfl_xor(s, off);
    if (lane == 0) cbnorm[r] = s;
}

// fp16 hi/lo planes (fallback paths only)
__global__ __launch_bounds__(256) void preconv_kernel(
    const float* __restrict__ cb, _Float16* __restrict__ bhi, _Float16* __restrict__ blo)
{
    size_t e4 = (size_t)blockIdx.x * 256 + threadIdx.x;
    float4 v = ((const float4*)cb)[e4];
    float t0 = v.x * 16.f, t1 = v.y * 16.f, t2 = v.z * 16.f, t3 = v.w * 16.f;
    _Float16 h0 = (_Float16)t0, h1 = (_Float16)t1, h2 = (_Float16)t2, h3 = (_Float16)t3;
    _Float16 l0 = (_Float16)((t0 - (float)h0) * 2048.f);
    _Float16 l1 = (_Float16)((t1 - (float)h1) * 2048.f);
    _Float16 l2 = (_Float16)((t2 - (float)h2) * 2048.f);
    _Float16 l3 = (_Float16)((t3 - (float)h3) * 2048.f);
    reinterpret_cast<half4*>(bhi)[e4] = half4{h0, h1, h2, h3};
    reinterpret_cast<half4*>(blo)[e4] = half4{l0, l1, l2, l3};
}

// z -> pre-swizzled fp16 tile image + fused znorm
__global__ __launch_bounds__(256) void preconv_z_kernel(
    const float* __restrict__ z, _Float16* __restrict__ zg, float* __restrict__ znorm)
{
    int gid = blockIdx.x * 256 + threadIdx.x;    // 0..1048575
    int row = gid >> 5;
    int g   = gid & 31;
    int r   = row & 63;
    const float4* src = (const float4*)z + (size_t)row * D4 + g * 2;
    float4 a = src[0], b = src[1];
    half8 h = { (_Float16)a.x, (_Float16)a.y, (_Float16)a.z, (_Float16)a.w,
                (_Float16)b.x, (_Float16)b.y, (_Float16)b.z, (_Float16)b.w };
    int gp = g ^ (r & 7);
    *reinterpret_cast<half8*>((char*)zg + (size_t)(row >> 6) * 32768 + r * 512 + gp * 16) = h;
    float s = a.x*a.x + a.y*a.y + a.z*a.z + a.w*a.w
            + b.x*b.x + b.y*b.y + b.z*b.z + b.w*b.w;
    #pragma unroll
    for (int off = 1; off < 32; off <<= 1) s += __shfl_xor(s, off);
    if ((threadIdx.x & 31) == 0) znorm[row] = s;
}

// ---------------- stage 1 (r11-exact, UNTOUCHED): fp16 MFMA ----------------
__global__ __launch_bounds__(256, 4) void vq_fp16_v11(
    const _Float16* __restrict__ zg,
    const _Float16* __restrict__ bhip, const float* __restrict__ cbnorm,
    float* __restrict__ pd, float* __restrict__ ps, int* __restrict__ pk)
{
    __shared__ _Float16 zt[BM * DD];   // 32 KB (pre-swizzled image)

    const int tid  = threadIdx.x;
    const int lane = tid & 63;
    const int cg   = tid >> 6;
    const int l15  = lane & 15;
    const int lhi  = lane >> 4;
    const int slice = blockIdx.x & 7;
    const int grp   = blockIdx.x >> 3;

    const int A0 = l15 * 512 + ((lhi ^ (l15 & 3)) << 4) + (((l15 >> 2) & 1) << 6);
    int Ar[4];
    #pragma unroll
    for (int rf = 0; rf < 4; ++rf) Ar[rf] = A0 + rf * 8192;
    const char* zbase = (const char*)zt;

    const half8* bp = (const half8*)bhip + ((size_t)(slice * SLICE_K + cg * 32 + l15) * 32 + lhi);
    const float* cnp = cbnorm + slice * SLICE_K + cg * 32 + l15;
    const int kbase = slice * SLICE_K + cg * 32 + l15;

    #pragma unroll 1
    for (int j = 0; j < TILES_PER_BLOCK; ++j) {
        const int tileIdx = grp * TILES_PER_BLOCK + j;
        const int rowBase = tileIdx * BM;

        __syncthreads();
        {
            const float4* src = (const float4*)((const char*)zg + (size_t)tileIdx * 32768);
            float4* dst = (float4*)zt;
            #pragma unroll
            for (int i = 0; i < 8; ++i) dst[i * 256 + tid] = src[i * 256 + tid];
        }

        float bestd[4][4], secd[4][4];
        int   bestk[4][4];
        #pragma unroll
        for (int rf = 0; rf < 4; ++rf)
            #pragma unroll
            for (int reg = 0; reg < 4; ++reg) {
                bestd[rf][reg] = FLT_MAX; secd[rf][reg] = FLT_MAX; bestk[rf][reg] = 0;
            }

        __syncthreads();

        #pragma unroll 1
        for (int kt = 0; kt < SLICE_K / 128; ++kt) {
            floatx4 acc[4][2];
            #pragma unroll
            for (int rf = 0; rf < 4; ++rf)
                #pragma unroll
                for (int cf = 0; cf < 2; ++cf)
                    acc[rf][cf] = floatx4{0.f, 0.f, 0.f, 0.f};

            const half8* b0 = bp + kt * 4096;
            const half8* b1 = b0 + 512;

            #pragma unroll 2
            for (int dc = 0; dc < 8; ++dc) {
                half8 f0 = b0[dc * 4];
                half8 f1 = b1[dc * 4];
                #pragma unroll
                for (int rf = 0; rf < 4; ++rf) {
                    half8 a = *reinterpret_cast<const half8*>(zbase + (Ar[rf] ^ (dc << 6)));
                    acc[rf][0] = __builtin_amdgcn_mfma_f32_16x16x32_f16(a, f0, acc[rf][0], 0, 0, 0);
                    acc[rf][1] = __builtin_amdgcn_mfma_f32_16x16x32_f16(a, f1, acc[rf][1], 0, 0, 0);
                }
            }

            const float cn0 = cnp[kt * 128];
            const float cn1 = cnp[kt * 128 + 16];
            const int k0 = kbase + kt * 128;
            #pragma unroll
            for (int cf = 0; cf < 2; ++cf) {
                const float cn = cf ? cn1 : cn0;
                const int k = k0 + cf * 16;
                #pragma unroll
                for (int rf = 0; rf < 4; ++rf)
                    #pragma unroll
                    for (int reg = 0; reg < 4; ++reg) {
                        float m = fmaf(-0.125f, acc[rf][cf][reg], cn);
                        float w = fmaxf(bestd[rf][reg], m);
                        secd[rf][reg] = fminf(secd[rf][reg], w);
                        if (m < bestd[rf][reg]) { bestd[rf][reg] = m; bestk[rf][reg] = k; }
                    }
            }
        }

        #pragma unroll
        for (int off = 1; off < 16; off <<= 1) {
            #pragma unroll
            for (int rf = 0; rf < 4; ++rf)
                #pragma unroll
                for (int reg = 0; reg < 4; ++reg) {
                    float od = __shfl_xor(bestd[rf][reg], off);
                    int   ok = __shfl_xor(bestk[rf][reg], off);
                    float os = __shfl_xor(secd[rf][reg], off);
                    float hi = fmaxf(bestd[rf][reg], od);
                    secd[rf][reg] = fminf(fminf(secd[rf][reg], os), hi);
                    if (od < bestd[rf][reg] || (od == bestd[rf][reg] && ok < bestk[rf][reg])) {
                        bestd[rf][reg] = od; bestk[rf][reg] = ok;
                    }
                }
        }

        __syncthreads();
        float* dsc = reinterpret_cast<float*>(zt);
        int*   ksc = reinterpret_cast<int*>(zt) + 256;
        float* ssc = reinterpret_cast<float*>(zt) + 512;
        if (l15 == 0) {
            #pragma unroll
            for (int rf = 0; rf < 4; ++rf)
                #pragma unroll
                for (int reg = 0; reg < 4; ++reg) {
                    int rrow = rf * 16 + lhi * 4 + reg;
                    dsc[cg * 64 + rrow] = bestd[rf][reg];
                    ksc[cg * 64 + rrow] = bestk[rf][reg];
                    ssc[cg * 64 + rrow] = secd[rf][reg];
                }
        }
        __syncthreads();
        if (tid < 64) {
            float bd = dsc[tid];
            int   bk = ksc[tid];
            float sd = ssc[tid];
            #pragma unroll
            for (int c = 1; c < 4; ++c) {
                float od = dsc[c * 64 + tid];
                int   ok = ksc[c * 64 + tid];
                float os = ssc[c * 64 + tid];
                float hi = fmaxf(bd, od);
                sd = fminf(fminf(sd, os), hi);
                if (od < bd || (od == bd && ok < bk)) { bd = od; bk = ok; }
            }
            int row = rowBase + tid;
            pd[row * NSLICE + slice] = bd;
            ps[row * NSLICE + slice] = sd;
            pk[row * NSLICE + slice] = bk;
        }
    }
}

// r8 stage-1 fallback (reads raw z)
__global__ __launch_bounds__(256, 4) void vq_fp16_kernel(
    const float* __restrict__ z,
    const _Float16* __restrict__ bhip, const float* __restrict__ cbnorm,
    float* __restrict__ pd, float* __restrict__ ps, int* __restrict__ pk)
{
    __shared__ _Float16 zhi[BM * DD];
    const int tid  = threadIdx.x;
    const int lane = tid & 63;
    const int cg   = tid >> 6;
    const int l15  = lane & 15;
    const int lhi  = lane >> 4;
    const int slice = blockIdx.x & 7;
    const int grp   = blockIdx.x >> 3;
    const int sliceBase = slice * SLICE_K;

    int rowA[4];
    #pragma unroll
    for (int rf = 0; rf < 4; ++rf) rowA[rf] = rf * 16 + l15;

    #pragma unroll 1
    for (int j = 0; j < TILES_PER_BLOCK; ++j) {
        const int rowBase = (grp * TILES_PER_BLOCK + j) * BM;
        __syncthreads();
        #pragma unroll
        for (int i = 0; i < 16; ++i) {
            int gid = i * 256 + tid;
            int r   = gid >> 6;
            int c4  = gid & 63;
            float4 v = ((const float4*)z)[(size_t)(rowBase + r) * D4 + c4];
            _Float16 h0 = (_Float16)v.x, h1 = (_Float16)v.y,
                     h2 = (_Float16)v.z, h3 = (_Float16)v.w;
            int g = c4 >> 1;
            int byteOff = r * 512 + ((g ^ (r & 7)) << 4) + ((c4 & 1) << 3);
            *reinterpret_cast<half4*>(reinterpret_cast<char*>(zhi) + byteOff) = half4{h0, h1, h2, h3};
        }
        float bestd[4][4], secd[4][4];
        int   bestk[4][4];
        #pragma unroll
        for (int rf = 0; rf < 4; ++rf)
            #pragma unroll
            for (int reg = 0; reg < 4; ++reg) {
                bestd[rf][reg] = FLT_MAX; secd[rf][reg] = FLT_MAX; bestk[rf][reg] = 0;
            }
        __syncthreads();
        #pragma unroll 1
        for (int kt = 0; kt < SLICE_K / 128; ++kt) {
            floatx4 acc[4][2];
            #pragma unroll
            for (int rf = 0; rf < 4; ++rf)
                #pragma unroll
                for (int cf = 0; cf < 2; ++cf)
                    acc[rf][cf] = floatx4{0.f, 0.f, 0.f, 0.f};
            const int codeBase = sliceBase + kt * 128 + cg * 32 + l15;
            #pragma unroll 2
            for (int dc = 0; dc < 8; ++dc) {
                half8 bhi_f[2];
                #pragma unroll
                for (int cf = 0; cf < 2; ++cf) {
                    size_t off = (size_t)(codeBase + 16 * cf) * DD + dc * 32 + lhi * 8;
                    bhi_f[cf] = *reinterpret_cast<const half8*>(bhip + off);
                }
                #pragma unroll
                for (int rf = 0; rf < 4; ++rf) {
                    int g = dc * 4 + lhi;
                    int off = rowA[rf] * 512 + ((g ^ (rowA[rf] & 7)) << 4);
                    half8 ahi = *reinterpret_cast<const half8*>(reinterpret_cast<const char*>(zhi) + off);
                    #pragma unroll
                    for (int cf = 0; cf < 2; ++cf)
                        acc[rf][cf] = __builtin_amdgcn_mfma_f32_16x16x32_f16(ahi, bhi_f[cf], acc[rf][cf], 0, 0, 0);
                }
            }
            #pragma unroll
            for (int cf = 0; cf < 2; ++cf) {
                int k = codeBase + 16 * cf;
                float cn = cbnorm[k];
                #pragma unroll
                for (int rf = 0; rf < 4; ++rf)
                    #pragma unroll
                    for (int reg = 0; reg < 4; ++reg) {
                        float m = fmaf(-0.125f, acc[rf][cf][reg], cn);
                        float w = fmaxf(bestd[rf][reg], m);
                        secd[rf][reg] = fminf(secd[rf][reg], w);
                        if (m < bestd[rf][reg]) { bestd[rf][reg] = m; bestk[rf][reg] = k; }
                    }
            }
        }
        #pragma unroll
        for (int off = 1; off < 16; off <<= 1) {
            #pragma unroll
            for (int rf = 0; rf < 4; ++rf)
                #pragma unroll
                for (int reg = 0; reg < 4; ++reg) {
                    float od = __shfl_xor(bestd[rf][reg], off);
                    int   ok = __shfl_xor(bestk[rf][reg], off);
                    float os = __shfl_xor(secd[rf][reg], off);
                    float hi = fmaxf(bestd[rf][reg], od);
                    secd[rf][reg] = fminf(fminf(secd[rf][reg], os), hi);
                    if (od < bestd[rf][reg] || (od == bestd[rf][reg] && ok < bestk[rf][reg])) {
                        bestd[rf][reg] = od; bestk[rf][reg] = ok;
                    }
                }
        }
        __syncthreads();
        float* dsc = reinterpret_cast<float*>(zhi);
        int*   ksc = reinterpret_cast<int*>(zhi) + 256;
        float* ssc = reinterpret_cast<float*>(zhi) + 512;
        if (l15 == 0) {
            #pragma unroll
            for (int rf = 0; rf < 4; ++rf)
                #pragma unroll
                for (int reg = 0; reg < 4; ++reg) {
                    int rrow = rf * 16 + lhi * 4 + reg;
                    dsc[cg * 64 + rrow] = bestd[rf][reg];
                    ksc[cg * 64 + rrow] = bestk[rf][reg];
                    ssc[cg * 64 + rrow] = secd[rf][reg];
                }
        }
        __syncthreads();
        if (tid < 64) {
            float bd = dsc[tid];
            int   bk = ksc[tid];
            float sd = ssc[tid];
            #pragma unroll
            for (int c = 1; c < 4; ++c) {
                float od = dsc[c * 64 + tid];
                int   ok = ksc[c * 64 + tid];
                float os = ssc[c * 64 + tid];
                float hi = fmaxf(bd, od);
                sd = fminf(fminf(sd, os), hi);
                if (od < bd || (od == bd && ok < bk)) { bd = od; bk = ok; }
            }
            int row = rowBase + tid;
            pd[row * NSLICE + slice] = bd;
            ps[row * NSLICE + slice] = sd;
            pk[row * NSLICE + slice] = bk;
        }
    }
}

__global__ __launch_bounds__(256) void slice_reduce_kernel(
    const float* __restrict__ pd, const float* __restrict__ ps, const int* __restrict__ pk,
    int* __restrict__ codes, float* __restrict__ codes_f,
    int* __restrict__ cnt, int* __restrict__ list, float tau)
{
    int row = blockIdx.x * 256 + threadIdx.x;
    float bd = FLT_MAX, sd = FLT_MAX;
    int bk = 0;
    #pragma unroll
    for (int s = 0; s < NSLICE; ++s) {
        float d  = pd[row * NSLICE + s];
        int   k  = pk[row * NSLICE + s];
        float s2 = ps[row * NSLICE + s];
        float hi = fmaxf(bd, d);
        sd = fminf(fminf(sd, s2), hi);
        if (d < bd || (d == bd && k < bk)) { bd = d; bk = k; }
    }
    codes[row]   = bk;
    codes_f[row] = (float)bk;
    if ((sd - bd) < tau) {
        int idx = atomicAdd(cnt, 1);
        list[idx] = row;
    }
}

// exact fp32 refine of flagged rows: jobs = 32-row tile x 8 slices.
// z tile in LDS (broadcast reads); 8-row register blocking; round-1 numerics.
__global__ __launch_bounds__(256) void refine32_kernel(
    const float* __restrict__ z, const float* __restrict__ cb,
    const float* __restrict__ znorm, const float* __restrict__ cbnorm,
    const int* __restrict__ cnt, const int* __restrict__ list,
    float* __restrict__ pd2, int* __restrict__ pk2)
{
    __shared__ float zrows[BM2][DD];   // 32 KB
    __shared__ float znls[BM2];
    __shared__ float dsc[4][8];
    __shared__ int   ksc[4][8];
    const int n1 = *cnt;
    if (n1 == 0) return;
    const int ntiles = (n1 + BM2 - 1) / BM2;
    const int njobs = ntiles * NSLICE;
    const int tid  = threadIdx.x;
    const int lane = tid & 63;
    const int wv   = tid >> 6;

    for (int job = blockIdx.x; job < njobs; job += gridDim.x) {
        const int slice = job & 7;
        const int tile  = job >> 3;
        const int base  = tile * BM2;
        const int kbase = slice * SLICE_K;

        __syncthreads();
        for (int i = tid; i < BM2 * D4; i += 256) {
            int r = i >> 6, c4 = i & 63;
            int pos = base + r;
            int row = list[pos < n1 ? pos : n1 - 1];
            ((float4*)zrows[r])[c4] = ((const float4*)z)[(size_t)row * D4 + c4];
        }
        if (tid < BM2) {
            int pos = base + tid;
            znls[tid] = znorm[list[pos < n1 ? pos : n1 - 1]];
        }
        __syncthreads();

        #pragma unroll 1
        for (int rc = 0; rc < 4; ++rc) {
            float bd8[8];
            int   bk8[8];
            #pragma unroll
            for (int r8 = 0; r8 < 8; ++r8) { bd8[r8] = FLT_MAX; bk8[r8] = 0; }

            #pragma unroll 1
            for (int c = 0; c < 4; ++c) {           // k ascending per thread
                const int k = kbase + c * 256 + tid;
                const float4* crow = (const float4*)cb + (size_t)k * D4;
                float acc[8];
                #pragma unroll
                for (int r8 = 0; r8 < 8; ++r8) acc[r8] = 0.f;
                #pragma unroll 4
                for (int d4 = 0; d4 < D4; ++d4) {
                    float4 cv = crow[d4];
                    #pragma unroll
                    for (int r8 = 0; r8 < 8; ++r8) {
                        float4 zv = ((const float4*)zrows[rc * 8 + r8])[d4];
                        acc[r8] = fmaf(zv.x, cv.x, acc[r8]);
                        acc[r8] = fmaf(zv.y, cv.y, acc[r8]);
                        acc[r8] = fmaf(zv.z, cv.z, acc[r8]);
                        acc[r8] = fmaf(zv.w, cv.w, acc[r8]);
                    }
                }
                const float cn = cbnorm[k];
                #pragma unroll
                for (int r8 = 0; r8 < 8; ++r8) {
                    float dist = fmaf(-2.f, acc[r8], znls[rc * 8 + r8]) + cn;
                    if (dist < bd8[r8]) { bd8[r8] = dist; bk8[r8] = k; }
                }
            }

            // cross-lane lexicographic (d,k) reduce
            #pragma unroll
            for (int off = 1; off < 64; off <<= 1) {
                #pragma unroll
                for (int r8 = 0; r8 < 8; ++r8) {
                    float od = __shfl_xor(bd8[r8], off);
                    int   ok = __shfl_xor(bk8[r8], off);
                    if (od < bd8[r8] || (od == bd8[r8] && ok < bk8[r8])) {
                        bd8[r8] = od; bk8[r8] = ok;
                    }
                }
            }
            if (lane == 0) {
                #pragma unroll
                for (int r8 = 0; r8 < 8; ++r8) { dsc[wv][r8] = bd8[r8]; ksc[wv][r8] = bk8[r8]; }
            }
            __syncthreads();
            if (tid < 8) {
                float bd = dsc[0][tid];
                int   bk = ksc[0][tid];
                #pragma unroll
                for (int w = 1; w < 4; ++w) {
                    float od = dsc[w][tid];
                    int   ok = ksc[w][tid];
                    if (od < bd || (od == bd && ok < bk)) { bd = od; bk = ok; }
                }
                int pos = base + rc * 8 + tid;   // partials indexed by list position
                pd2[pos * NSLICE + slice] = bd;
                pk2[pos * NSLICE + slice] = bk;
            }
            __syncthreads();
        }
    }
}

// merge per-slice exact partials -> final codes for flagged rows
__global__ __launch_bounds__(256) void slice_merge_kernel(
    const float* __restrict__ pd2, const int* __restrict__ pk2,
    const int* __restrict__ cnt, const int* __restrict__ list,
    int* __restrict__ codes, float* __restrict__ codes_f)
{
    const int n1 = *cnt;
    for (int i = blockIdx.x * 256 + threadIdx.x; i < n1; i += gridDim.x * 256) {
        float bd = FLT_MAX;
        int bk = 0;
        #pragma unroll
        for (int s = 0; s < NSLICE; ++s) {
            float d = pd2[i * NSLICE + s];
            int   k = pk2[i * NSLICE + s];
            if (d < bd || (d == bd && k < bk)) { bd = d; bk = k; }
        }
        int row = list[i];
        codes[row]   = bk;
        codes_f[row] = (float)bk;
    }
}

// fallback-path per-row exact fp32 refine (round-1 numerics)
__global__ __launch_bounds__(256) void refine_kernel(
    const float* __restrict__ z, const float* __restrict__ cb,
    const float* __restrict__ znorm, const float* __restrict__ cbnorm,
    const int* __restrict__ cnt, const int* __restrict__ list,
    int* __restrict__ codes, float* __restrict__ codes_f)
{
    __shared__ float zrow[DD];
    __shared__ float dred[4];
    __shared__ int   kred[4];
    const int tid = threadIdx.x;
    const int lane = tid & 63;
    const int wv = tid >> 6;
    const int n = *cnt;
    for (int i = blockIdx.x; i < n; i += gridDim.x) {
        const int row = list[i];
        if (tid < 64) ((float4*)zrow)[tid] = ((const float4*)z)[(size_t)row * D4 + tid];
        const float zn = znorm[row];
        __syncthreads();
        float bd = FLT_MAX;
        int   bk = 0;
        for (int k = tid; k < KK; k += 256) {
            const float4* crow = (const float4*)cb + (size_t)k * D4;
            float acc = 0.f;
            #pragma unroll 8
            for (int d4 = 0; d4 < D4; ++d4) {
                float4 c = crow[d4];
                float4 zv = ((const float4*)zrow)[d4];
                acc = fmaf(zv.x, c.x, acc);
                acc = fmaf(zv.y, c.y, acc);
                acc = fmaf(zv.z, c.z, acc);
                acc = fmaf(zv.w, c.w, acc);
            }
            float dist = fmaf(-2.f, acc, zn) + cbnorm[k];
            if (dist < bd) { bd = dist; bk = k; }
        }
        #pragma unroll
        for (int off = 1; off < 64; off <<= 1) {
            float od = __shfl_xor(bd, off);
            int   ok = __shfl_xor(bk, off);
            if (od < bd || (od == bd && ok < bk)) { bd = od; bk = ok; }
        }
        if (lane == 0) { dred[wv] = bd; kred[wv] = bk; }
        __syncthreads();
        if (tid == 0) {
            #pragma unroll
            for (int c = 1; c < 4; ++c) {
                if (dred[c] < bd || (dred[c] == bd && kred[c] < bk)) { bd = dred[c]; bk = kred[c]; }
            }
            codes[row]   = bk;
            codes_f[row] = (float)bk;
        }
        __syncthreads();
    }
}

__global__ __launch_bounds__(256) void gather_loss_kernel(
    const float* __restrict__ z, const float* __restrict__ cb,
    const int* __restrict__ codes, float* __restrict__ zq_out,
    float* __restrict__ partials)
{
    __shared__ float red[4];
    int tid = threadIdx.x;
    size_t e4 = (size_t)blockIdx.x * 256 + tid;
    int row = (int)(e4 >> 6);
    int d4  = (int)(e4 & 63);
    int code = codes[row];
    float4 q  = ((const float4*)cb)[(size_t)code * D4 + d4];
    float4 zv = ((const float4*)z)[e4];
    float dx = q.x - zv.x, dy = q.y - zv.y, dz = q.z - zv.z, dw = q.w - zv.w;
    float4 o;
    o.x = zv.x + dx; o.y = zv.y + dy; o.z = zv.z + dz; o.w = zv.w + dw;
    ((float4*)zq_out)[e4] = o;
    float s = dx*dx + dy*dy + dz*dz + dw*dw;
    #pragma unroll
    for (int off = 1; off < 64; off <<= 1) s += __shfl_xor(s, off);
    if ((tid & 63) == 0) red[tid >> 6] = s;
    __syncthreads();
    if (tid == 0) partials[blockIdx.x] = ((red[0] + red[1]) + red[2]) + red[3];
}

__global__ __launch_bounds__(256) void final_loss_kernel(
    const float* __restrict__ partials, float* __restrict__ out_loss)
{
    __shared__ float red[4];
    int tid = threadIdx.x;
    float s = 0.f;
    #pragma unroll 4
    for (int i = 0; i < 32; ++i) s += partials[tid * 32 + i];
    #pragma unroll
    for (int off = 1; off < 64; off <<= 1) s += __shfl_xor(s, off);
    if ((tid & 63) == 0) red[tid >> 6] = s;
    __syncthreads();
    if (tid == 0) {
        float tot = ((red[0] + red[1]) + red[2]) + red[3];
        out_loss[0] = 0.5f * (tot / (float)NELEM);
    }
}

// round-4 fallback kernel (tiny-ws path)
template <bool PRECONV, bool REFINE>
__global__ __launch_bounds__(512, 1) void vq_mfma_kernel(
    const float* __restrict__ z, const float* __restrict__ cb,
    const _Float16* __restrict__ bhip, const _Float16* __restrict__ blop,
    const float* __restrict__ znorm, const float* __restrict__ cbnorm,
    int* __restrict__ codes, float* __restrict__ codes_f,
    int* __restrict__ cnt, int* __restrict__ list)
{
    __shared__ _Float16 zhi[BM4 * DD];
    __shared__ _Float16 zlo[BM4 * DD];
    const int tid  = threadIdx.x;
    const int lane = tid & 63;
    const int w    = tid >> 6;
    const int rg   = w >> 2;
    const int cg   = w & 3;
    const int l15  = lane & 15;
    const int lhi  = lane >> 4;
    const int rowBase = blockIdx.x * BM4;

    #pragma unroll
    for (int i = 0; i < 16; ++i) {
        int gid = i * 512 + tid;
        int r   = gid >> 6;
        int c4  = gid & 63;
        float4 v = ((const float4*)z)[(size_t)(rowBase + r) * D4 + c4];
        _Float16 h0 = (_Float16)v.x, h1 = (_Float16)v.y,
                 h2 = (_Float16)v.z, h3 = (_Float16)v.w;
        _Float16 e0 = (_Float16)((v.x - (float)h0) * 2048.f);
        _Float16 e1 = (_Float16)((v.y - (float)h1) * 2048.f);
        _Float16 e2 = (_Float16)((v.z - (float)h2) * 2048.f);
        _Float16 e3 = (_Float16)((v.w - (float)h3) * 2048.f);
        int g = c4 >> 1;
        int byteOff = r * 512 + (((g ^ (r & 7))) << 4) + ((c4 & 1) << 3);
        *reinterpret_cast<half4*>(reinterpret_cast<char*>(zhi) + byteOff) = half4{h0, h1, h2, h3};
        *reinterpret_cast<half4*>(reinterpret_cast<char*>(zlo) + byteOff) = half4{e0, e1, e2, e3};
    }
    int rowA[4];
    #pragma unroll
    for (int rf = 0; rf < 4; ++rf) rowA[rf] = rg * 64 + rf * 16 + l15;
    float zn[4][4];
    #pragma unroll
    for (int rf = 0; rf < 4; ++rf)
        #pragma unroll
        for (int reg = 0; reg < 4; ++reg)
            zn[rf][reg] = znorm[rowBase + rg * 64 + rf * 16 + lhi * 4 + reg];
    float bestd[4][4], secd[4][4];
    int   bestk[4][4];
    #pragma unroll
    for (int rf = 0; rf < 4; ++rf)
        #pragma unroll
        for (int reg = 0; reg < 4; ++reg) {
            bestd[rf][reg] = FLT_MAX; secd[rf][reg] = FLT_MAX; bestk[rf][reg] = 0;
        }
    __syncthreads();
    for (int kt = 0; kt < KK / 256; ++kt) {
        floatx4 accH[4][4], accM[4][4];
        #pragma unroll
        for (int rf = 0; rf < 4; ++rf)
            #pragma unroll
            for (int cf = 0; cf < 4; ++cf) {
                accH[rf][cf] = floatx4{0.f, 0.f, 0.f, 0.f};
                accM[rf][cf] = floatx4{0.f, 0.f, 0.f, 0.f};
            }
        const int codeBase = kt * 256 + cg * 64 + l15;
        for (int dc = 0; dc < 8; ++dc) {
            half8 bhi_f[4], blo_f[4];
            #pragma unroll
            for (int cf = 0; cf < 4; ++cf) {
                if (PRECONV) {
                    size_t off = (size_t)(codeBase + 16 * cf) * DD + dc * 32 + lhi * 8;
                    bhi_f[cf] = *reinterpret_cast<const half8*>(bhip + off);
                    blo_f[cf] = *reinterpret_cast<const half8*>(blop + off);
                } else {
                    const float4* p = (const float4*)(cb + (size_t)(codeBase + 16 * cf) * DD + dc * 32 + lhi * 8);
                    float4 u0 = p[0];
                    float4 u1 = p[1];
                    float uv[8] = {u0.x, u0.y, u0.z, u0.w, u1.x, u1.y, u1.z, u1.w};
                    half8 bh, bl;
                    #pragma unroll
                    for (int jj = 0; jj < 8; ++jj) {
                        float t = uv[jj] * 16.f;
                        _Float16 h = (_Float16)t;
                        bh[jj] = h;
                        bl[jj] = (_Float16)((t - (float)h) * 2048.f);
                    }
                    bhi_f[cf] = bh; blo_f[cf] = bl;
                }
            }
            #pragma unroll
            for (int rf = 0; rf < 4; ++rf) {
                int g = dc * 4 + lhi;
                int off = rowA[rf] * 512 + ((g ^ (rowA[rf] & 7)) << 4);
                half8 ahi = *reinterpret_cast<const half8*>(reinterpret_cast<const char*>(zhi) + off);
                half8 alo = *reinterpret_cast<const half8*>(reinterpret_cast<const char*>(zlo) + off);
                #pragma unroll
                for (int cf = 0; cf < 4; ++cf) {
                    accH[rf][cf] = __builtin_amdgcn_mfma_f32_16x16x32_f16(ahi, bhi_f[cf], accH[rf][cf], 0, 0, 0);
                    accM[rf][cf] = __builtin_amdgcn_mfma_f32_16x16x32_f16(alo, bhi_f[cf], accM[rf][cf], 0, 0, 0);
                    accM[rf][cf] = __builtin_amdgcn_mfma_f32_16x16x32_f16(ahi, blo_f[cf], accM[rf][cf], 0, 0, 0);
                }
            }
        }
        #pragma unroll
        for (int cf = 0; cf < 4; ++cf) {
            int k = codeBase + 16 * cf;
            float cn = cbnorm[k];
            #pragma unroll
            for (int rf = 0; rf < 4; ++rf)
                #pragma unroll
                for (int reg = 0; reg < 4; ++reg) {
                    float dot16 = fmaf(accM[rf][cf][reg], 0x1p-11f, accH[rf][cf][reg]);
                    float dist  = fmaf(-0.125f, dot16, zn[rf][reg]) + cn;
                    float wv2 = fmaxf(bestd[rf][reg], dist);
                    secd[rf][reg] = fminf(secd[rf][reg], wv2);
                    if (dist < bestd[rf][reg]) { bestd[rf][reg] = dist; bestk[rf][reg] = k; }
                }
        }
    }
    #pragma unroll
    for (int off = 1; off < 16; off <<= 1) {
        #pragma unroll
        for (int rf = 0; rf < 4; ++rf)
            #pragma unroll
            for (int reg = 0; reg < 4; ++reg) {
                float od = __shfl_xor(bestd[rf][reg], off);
                int   ok = __shfl_xor(bestk[rf][reg], off);
                float os = __shfl_xor(secd[rf][reg], off);
                float hi = fmaxf(bestd[rf][reg], od);
                secd[rf][reg] = fminf(fminf(secd[rf][reg], os), hi);
                if (od < bestd[rf][reg] || (od == bestd[rf][reg] && ok < bestk[rf][reg])) {
                    bestd[rf][reg] = od; bestk[rf][reg] = ok;
                }
            }
    }
    __syncthreads();
    float* dsc = reinterpret_cast<float*>(zhi);
    int*   ksc = reinterpret_cast<int*>(zhi) + 512;
    float* ssc = reinterpret_cast<float*>(zhi) + 1024;
    if (l15 == 0) {
        #pragma unroll
        for (int rf = 0; rf < 4; ++rf)
            #pragma unroll
            for (int reg = 0; reg < 4; ++reg) {
                int rrow = rg * 64 + rf * 16 + lhi * 4 + reg;
                dsc[cg * 128 + rrow] = bestd[rf][reg];
                ksc[cg * 128 + rrow] = bestk[rf][reg];
                ssc[cg * 128 + rrow] = secd[rf][reg];
            }
    }
    __syncthreads();
    if (tid < 128) {
        float bd = dsc[tid];
        int   bk = ksc[tid];
        float sd = ssc[tid];
        #pragma unroll
        for (int c = 1; c < 4; ++c) {
            float od = dsc[c * 128 + tid];
            int   ok = ksc[c * 128 + tid];
            float os = ssc[c * 128 + tid];
            float hi = fmaxf(bd, od);
            sd = fminf(fminf(sd, os), hi);
            if (od < bd || (od == bd && ok < bk)) { bd = od; bk = ok; }
        }
        int row = rowBase + tid;
        codes[row]   = bk;
        codes_f[row] = (float)bk;
        if (REFINE && (sd - bd) < TAU2) {
            int idx = atomicAdd(cnt, 1);
            list[idx] = row;
        }
    }
}

extern "C" void kernel_launch(void* const* d_in, const int* in_sizes, int n_in,
                              void* d_out, int out_size, void* d_ws, size_t ws_size,
                              hipStream_t stream) {
    const float* z  = (const float*)d_in[0];
    const float* cb = (const float*)d_in[1];
    float* out      = (float*)d_out;
    float* zq_out   = out;
    float* loss_out = out + NELEM;
    float* codes_f  = out + NELEM + 1;

    char* wsb       = (char*)d_ws;
    float* znorm    = (float*)(wsb + 0);
    float* cbnorm   = (float*)(wsb + 131072);
    int*   codes    = (int*)(wsb + 163840);
    float* partials = (float*)(wsb + 294912);
    int*   cnt      = (int*)(wsb + 327680);
    int*   list     = (int*)(wsb + 327696);

    if (ws_size >= (size_t)WS_V9_BYTES) {
        float* pd     = (float*)(wsb + 593920);
        float* ps     = (float*)(wsb + 1642496);
        int*   pk     = (int*)(wsb + 2691072);
        _Float16* bhi = (_Float16*)(wsb + 4194304);
        _Float16* zg  = (_Float16*)(wsb + 12582912);
        // exact-refine partials reuse zg region (dead after stage-1)
        float* pd2    = (float*)(wsb + 12582912);
        int*   pk2    = (int*)(wsb + 12582912 + 2097152);

        hipMemsetAsync(cnt, 0, 8, stream);
        prep_cb_kernel<<<2048, 256, 0, stream>>>(cb, cbnorm, bhi);
        preconv_z_kernel<<<4096, 256, 0, stream>>>(z, zg, znorm);
        vq_fp16_v11<<<NBLOCKS1, 256, 0, stream>>>(zg, bhi, cbnorm, pd, ps, pk);
        slice_reduce_kernel<<<128, 256, 0, stream>>>(pd, ps, pk, codes, codes_f, cnt, list, TAU1);
        refine32_kernel<<<512, 256, 0, stream>>>(z, cb, znorm, cbnorm, cnt, list, pd2, pk2);
        slice_merge_kernel<<<64, 256, 0, stream>>>(pd2, pk2, cnt, list, codes, codes_f);
    } else if (ws_size >= (size_t)WS_CASCADE_BYTES) {
        float* pd     = (float*)(wsb + 593920);
        float* ps     = (float*)(wsb + 1642496);
        int*   pk     = (int*)(wsb + 2691072);
        _Float16* bhi = (_Float16*)(wsb + 4194304);
        _Float16* blo = (_Float16*)(wsb + 8388608);
        hipMemsetAsync(cnt, 0, 8, stream);
        norms_kernel<<<10240, 256, 0, stream>>>(z, cb, znorm, cbnorm);
        preconv_kernel<<<2048, 256, 0, stream>>>(cb, bhi, blo);
        vq_fp16_kernel<<<NBLOCKS1, 256, 0, stream>>>(z, bhi, cbnorm, pd, ps, pk);
        slice_reduce_kernel<<<128, 256, 0, stream>>>(pd, ps, pk, codes, codes_f, cnt, list, TAU1);
        refine_kernel<<<256, 256, 0, stream>>>(z, cb, znorm, cbnorm, cnt, list, codes, codes_f);
    } else {
        _Float16* bhi = (_Float16*)(wsb + 460800);
        _Float16* blo = (_Float16*)(wsb + 4655104);
        const bool preconv = ws_size >= (size_t)WS_R4_FULL_BYTES;
        const bool refine  = ws_size >= (size_t)WS_R4_REFINE_BYTES;
        norms_kernel<<<10240, 256, 0, stream>>>(z, cb, znorm, cbnorm);
        if (refine) hipMemsetAsync(cnt, 0, sizeof(int), stream);
        if (preconv) preconv_kernel<<<2048, 256, 0, stream>>>(cb, bhi, blo);
        if (preconv && refine)
            vq_mfma_kernel<true, true><<<NROWS / BM4, 512, 0, stream>>>(z, cb, bhi, blo, znorm, cbnorm, codes, codes_f, cnt, list);
        else if (preconv)
            vq_mfma_kernel<true, false><<<NROWS / BM4, 512, 0, stream>>>(z, cb, bhi, blo, znorm, cbnorm, codes, codes_f, cnt, list);
        else if (refine)
            vq_mfma_kernel<false, true><<<NROWS / BM4, 512, 0, stream>>>(z, cb, bhi, blo, znorm, cbnorm, codes, codes_f, cnt, list);
        else
            vq_mfma_kernel<false, false><<<NROWS / BM4, 512, 0, stream>>>(z, cb, bhi, blo, znorm, cbnorm, codes, codes_f, cnt, list);
        if (refine)
            refine_kernel<<<256, 256, 0, stream>>>(z, cb, znorm, cbnorm, cnt, list, codes, codes_f);
    }

    gather_loss_kernel<<<8192, 256, 0, stream>>>(z, cb, codes, zq_out, partials);
    final_loss_kernel<<<1, 256, 0, stream>>>(partials, loss_out);
}